// Round 9
// baseline (265.678 us; speedup 1.0000x reference)
//
#include <hip/hip_runtime.h>

#define N_NODES 100000
#define N_EDGES 3200000
#define N_GRAPHS 512
#define IN_CH 50
#define HID 256
#define NB 391          // buckets of 256 nodes
#define NBLK2 391       // edge blocks (block-local sort)
#define EPB2 8192       // edges per block

typedef unsigned short ushort_t;
using s16x8 = __attribute__((ext_vector_type(8))) short;
using us8   = __attribute__((ext_vector_type(8))) unsigned short;
using us4   = __attribute__((ext_vector_type(4))) unsigned short;
using f32x4 = __attribute__((ext_vector_type(4))) float;
using f32x2 = __attribute__((ext_vector_type(2))) float;

__device__ __forceinline__ float bf2f(ushort_t u) {
    return __uint_as_float(((unsigned int)u) << 16);
}
__device__ __forceinline__ ushort_t f2bf(float f) {
    unsigned int x = __float_as_uint(f);
    unsigned int r = x + 0x7fffu + ((x >> 16) & 1u);
    return (ushort_t)(r >> 16);
}
__device__ __forceinline__ int clampi(int v, int hi) {
    return v < 0 ? 0 : (v >= hi ? hi - 1 : v);
}

// fp8 e4m3fn encode (RNE, saturate to 448) / decode
__device__ __forceinline__ unsigned char f2e4(float f) {
    unsigned char s = (unsigned char)((__float_as_uint(f) >> 31) << 7);
    float a = fabsf(f);
    if (a >= 0.015625f) {
        if (a > 448.f) a = 448.f;
        unsigned int u = __float_as_uint(a);
        u += 0x7FFFFu + ((u >> 20) & 1u);     // RNE into 3-bit mantissa
        int e8 = (int)(u >> 23) - 127 + 7;
        unsigned int m8 = (u >> 20) & 7u;
        if (e8 > 15) { e8 = 15; m8 = 6; }
        return s | (unsigned char)((e8 << 3) | m8);
    } else {
        int m = (int)rintf(a * 512.f);
        if (m > 7) return s | 0x08;
        return s | (unsigned char)m;
    }
}
// branchless e4m3 -> f32: exact for normals AND denormals (bit-place + 2^120 scale)
__device__ __forceinline__ float e42f(unsigned int c) {
    unsigned int w = ((c & 0x80u) << 24) | ((c & 0x7fu) << 20);
    return __uint_as_float(w) * 0x1p120f;
}

// Packed fp8 decode + packed FMA accumulate into f32x2 pairs.
#if __has_builtin(__builtin_amdgcn_cvt_pk_f32_fp8)
#define ACC4(w, m, pb)                                                     \
    do {                                                                   \
        f32x2 p01 = __builtin_amdgcn_cvt_pk_f32_fp8((int)(w), false);      \
        f32x2 p23 = __builtin_amdgcn_cvt_pk_f32_fp8((int)(w), true);       \
        a2[(pb) + 0] = p01 * (m) + a2[(pb) + 0];                           \
        a2[(pb) + 1] = p23 * (m) + a2[(pb) + 1];                           \
    } while (0)
#else
#define ACC4(w, m, pb)                                                     \
    do {                                                                   \
        f32x2 p01, p23;                                                    \
        p01[0] = e42f((w) & 0xffu);        p01[1] = e42f(((w) >> 8) & 0xffu);  \
        p23[0] = e42f(((w) >> 16) & 0xffu); p23[1] = e42f(((w) >> 24) & 0xffu); \
        a2[(pb) + 0] = p01 * (m) + a2[(pb) + 0];                           \
        a2[(pb) + 1] = p23 * (m) + a2[(pb) + 1];                           \
    } while (0)
#endif

// ---- workspace layout (bytes); proven ws_size >= 39,272,064 ----
constexpr size_t OFF_GACC   = 0;          // 512*2*4 = 4096
constexpr size_t OFF_BASE   = 6144;       // (NB+1)*4 = 1568
constexpr size_t ZBYTES     = 8192;       // zeroed prefix
constexpr size_t OFF_SD     = 161536;     // packed (start<<10|deg) u32 [N] = 400000
constexpr size_t OFF_SRC    = 561536;     // int [E] = 12.8MB (alive through gather)
constexpr size_t OFF_X8     = 13361536;   // fp8 [N,64] = 6.4MB
constexpr size_t OFF_EP     = 19761536;   // int [391][8192] = 12,812,288; agg bf16 [N,64] overlays
constexpr size_t OFF_WT     = 32573824;   // bf16 [256][128] = 65536 -> 32,639,360
constexpr size_t OFF_BND    = 32639360;   // int [N_GRAPHS+1] = 2052 -> 32,641,412
constexpr size_t OFF_LST    = 32641416;   // u16 [391][392] = 306,544 -> 32,947,960

// P1 v3: block-local counting sort (single pass, no global placement).
// Block blk sorts its 8192 edges by bucket into ep[blk*EPB2 ...] (coalesced)
// and writes its run-offset row lst[blk][0..NB] (u16, exclusive scan + total).
__global__ __launch_bounds__(512) void k_scatter(const int* __restrict__ ei,
                                                 int* __restrict__ ep,
                                                 ushort_t* __restrict__ lst) {
    __shared__ int hist[NB];
    __shared__ int sa[512];
    __shared__ int sorig[512];
    __shared__ int lstart[NB + 1];
    __shared__ int lcur[NB];
    __shared__ unsigned int eph[EPB2];

    const int blk = blockIdx.x, t = threadIdx.x;
    for (int i = t; i < NB; i += 512) hist[i] = 0;
    __syncthreads();
    const int e0 = blk * EPB2;
    int sv[16], dv[16];
#pragma unroll
    for (int j = 0; j < 16; ++j) {
        int e = e0 + j * 512 + t;
        if (e < N_EDGES) {
            sv[j] = clampi(ei[e], N_NODES);
            dv[j] = clampi(ei[N_EDGES + e], N_NODES);
        } else {
            dv[j] = -1;
        }
    }
#pragma unroll
    for (int j = 0; j < 16; ++j)
        if (dv[j] >= 0) atomicAdd(&hist[dv[j] >> 8], 1);
    __syncthreads();
    // 512-wide Hillis-Steele scan over NB buckets
    int v = (t < NB) ? hist[t] : 0;
    sa[t] = v; sorig[t] = v;
    __syncthreads();
    for (int off = 1; off < 512; off <<= 1) {
        int u = (t >= off) ? sa[t - off] : 0;
        __syncthreads();
        sa[t] += u;
        __syncthreads();
    }
    if (t < NB) { lstart[t] = sa[t] - sorig[t]; lcur[t] = sa[t] - sorig[t]; }
    if (t == NB - 1) lstart[NB] = sa[t];
    __syncthreads();
#pragma unroll
    for (int j = 0; j < 16; ++j) {
        if (dv[j] >= 0) {
            int b = dv[j] >> 8;
            int r = atomicAdd(&lcur[b], 1);
            eph[r] = ((unsigned int)sv[j] << 8) | (unsigned int)(dv[j] & 255);
        }
    }
    __syncthreads();
    int mv = lstart[NB];
    for (int i = t; i < mv; i += 512) ep[e0 + i] = (int)eph[i];
    for (int i = t; i <= NB; i += 512) lst[blk * (NB + 1) + i] = (ushort_t)lstart[i];
}

// P2a v2: per-bucket totals from the lst table
__global__ __launch_bounds__(128) void k_colsum(const ushort_t* __restrict__ lst,
                                                int* __restrict__ base) {
    __shared__ int part[128];
    int b = blockIdx.x, t = threadIdx.x;
    int s = 0;
    for (int blk = t; blk < NBLK2; blk += 128) {
        int ls = lst[blk * (NB + 1) + b];
        int le = lst[blk * (NB + 1) + b + 1];
        s += le - ls;
    }
    part[t] = s;
    __syncthreads();
    for (int off = 64; off > 0; off >>= 1) {
        if (t < off) part[t] += part[t + off];
        __syncthreads();
    }
    if (t == 0) base[b] = part[0];
}

// P2b: exclusive scan over bucket totals
__global__ __launch_bounds__(512) void k_scan_bucket(int* __restrict__ base) {
    __shared__ int a[512];
    __shared__ int orig[512];
    int t = threadIdx.x;
    int v = (t < NB) ? base[t] : 0;
    orig[t] = v; a[t] = v;
    __syncthreads();
    for (int off = 1; off < 512; off <<= 1) {
        int u = (t >= off) ? a[t - off] : 0;
        __syncthreads();
        a[t] += u;
        __syncthreads();
    }
    if (t < NB) base[t] = a[t] - orig[t];
    if (t == NB - 1) base[NB] = a[t];
}

// P4 v3: per-bucket fine CSR from block-local runs; srcs staged in LDS, flushed coalesced.
#define CSR_CAP 10240
__global__ __launch_bounds__(256) void k_csr(const int* __restrict__ ep,
                                             const ushort_t* __restrict__ lst,
                                             const int* __restrict__ base,
                                             int* __restrict__ srcs,
                                             unsigned int* __restrict__ sd) {
    __shared__ int ldeg[256];
    __shared__ int a[256];
    __shared__ int lcur[256];
    __shared__ int lds_src[CSR_CAP];
    int b = blockIdx.x, t = threadIdx.x;
    int e0 = base[b];
    int m = base[b + 1] - e0;
    ldeg[t] = 0;
    __syncthreads();
    for (int blk = t; blk < NBLK2; blk += 256) {
        int ls = lst[blk * (NB + 1) + b];
        int le = lst[blk * (NB + 1) + b + 1];
        const int* run = ep + blk * EPB2;
        for (int i = ls; i < le; ++i) atomicAdd(&ldeg[run[i] & 255], 1);
    }
    __syncthreads();
    a[t] = ldeg[t];
    __syncthreads();
    for (int off = 1; off < 256; off <<= 1) {
        int u = (t >= off) ? a[t - off] : 0;
        __syncthreads();
        a[t] += u;
        __syncthreads();
    }
    int excl = a[t] - ldeg[t];
    lcur[t] = excl;
    __syncthreads();
    int n = (b << 8) + t;
    if (n < N_NODES) {
        int dgc = ldeg[t] < 1023 ? ldeg[t] : 1023;
        sd[n] = ((unsigned int)(e0 + excl) << 10) | (unsigned int)dgc;
    }
    if (m <= CSR_CAP) {
        for (int blk = t; blk < NBLK2; blk += 256) {
            int ls = lst[blk * (NB + 1) + b];
            int le = lst[blk * (NB + 1) + b + 1];
            const int* run = ep + blk * EPB2;
            for (int i = ls; i < le; ++i) {
                int p = run[i];
                int r = atomicAdd(&lcur[p & 255], 1);
                lds_src[r] = p >> 8;
            }
        }
        __syncthreads();
        for (int i = t; i < m; i += 256) srcs[e0 + i] = lds_src[i];
    } else {
        for (int blk = t; blk < NBLK2; blk += 256) {
            int ls = lst[blk * (NB + 1) + b];
            int le = lst[blk * (NB + 1) + b + 1];
            const int* run = ep + blk * EPB2;
            for (int i = ls; i < le; ++i) {
                int p = run[i];
                int r = atomicAdd(&lcur[p & 255], 1);
                srcs[e0 + r] = p >> 8;
            }
        }
    }
}

// K4 fused prep: [0,25000) conv8 | [25000,25128) buildW | [25128,25519) bounds
#define PREP_CONV_BLOCKS 25000
#define PREP_BW_BLOCKS 128
#define PREP_BND_BLOCKS 391
__global__ __launch_bounds__(256) void k_prep(const float* __restrict__ x,
                                              unsigned char* __restrict__ x8,
                                              const float* __restrict__ Wl,
                                              const float* __restrict__ Wr,
                                              ushort_t* __restrict__ WT,
                                              const int* __restrict__ batch,
                                              int* __restrict__ bnd) {
    int blk = blockIdx.x;
    if (blk < PREP_CONV_BLOCKS) {
        int t = blk * 256 + threadIdx.x;
        int n = t >> 6, c = t & 63;
        x8[t] = (c < IN_CH) ? f2e4(x[n * IN_CH + c]) : (unsigned char)0;
    } else if (blk < PREP_CONV_BLOCKS + PREP_BW_BLOCKS) {
        int idx = (blk - PREP_CONV_BLOCKS) * 256 + threadIdx.x;
        int j = idx >> 7;
        int k = idx & 127;
        ushort_t val = 0;
        if (k < IN_CH) val = f2bf(Wl[j * IN_CH + k]);
        else if (k >= 64 && k < 64 + IN_CH) val = f2bf(Wr[j * IN_CH + (k - 64)]);
        WT[idx] = val;
    } else {
        int n = (blk - PREP_CONV_BLOCKS - PREP_BW_BLOCKS) * 256 + threadIdx.x;
        if (n >= N_NODES) return;
        int b = clampi(batch[n], N_GRAPHS);
        if (n == 0) {
            for (int g = 0; g <= b; ++g) bnd[g] = 0;
        } else {
            int a = clampi(batch[n - 1], N_GRAPHS);
            for (int g = a + 1; g <= b; ++g) bnd[g] = n;
        }
        if (n == N_NODES - 1) {
            for (int g = b + 1; g <= N_GRAPHS; ++g) bnd[g] = N_NODES;
        }
    }
}

// K5 v5: wave-per-node gather mean from fp8 x8; packed cvt + packed FMA.
__global__ __launch_bounds__(256) void k_gather8(const unsigned char* __restrict__ x8,
                          const unsigned int* __restrict__ sd,
                          const int* __restrict__ srcs, ushort_t* __restrict__ agg) {
    int gid = (blockIdx.x * blockDim.x + threadIdx.x) >> 6;
    int lane = threadIdx.x & 63;
    if (gid >= N_NODES) return;
    int r8 = lane >> 3;          // row within group of 8
    int c8 = lane & 7;           // byte-octet within 64B row
    unsigned int v = sd[gid];
    int dg = (int)(v & 1023u);
    int st = (int)(v >> 10);

    f32x2 a2[4] = {};            // 8 channels as 4 packed pairs

    const int nit = (dg + 31) >> 5;
    const int cb = c8 << 3;      // byte offset within row
    for (int it = 0; it < nit; ++it) {
        int i0 = (it << 5) + r8;
        int i1 = i0 + 8, i2 = i0 + 16, i3 = i0 + 24;
        int s0 = srcs[st + (i0 < dg ? i0 : 0)];
        int s1 = srcs[st + (i1 < dg ? i1 : 0)];
        int s2 = srcs[st + (i2 < dg ? i2 : 0)];
        int s3 = srcs[st + (i3 < dg ? i3 : 0)];
        uint2 w0 = *(const uint2*)(x8 + (size_t)s0 * 64 + cb);
        uint2 w1 = *(const uint2*)(x8 + (size_t)s1 * 64 + cb);
        uint2 w2 = *(const uint2*)(x8 + (size_t)s2 * 64 + cb);
        uint2 w3 = *(const uint2*)(x8 + (size_t)s3 * 64 + cb);
        float m0 = i0 < dg ? 1.f : 0.f;
        float m1 = i1 < dg ? 1.f : 0.f;
        float m2 = i2 < dg ? 1.f : 0.f;
        float m3 = i3 < dg ? 1.f : 0.f;
        ACC4(w0.x, m0, 0); ACC4(w0.y, m0, 2);
        ACC4(w1.x, m1, 0); ACC4(w1.y, m1, 2);
        ACC4(w2.x, m2, 0); ACC4(w2.y, m2, 2);
        ACC4(w3.x, m3, 0); ACC4(w3.y, m3, 2);
    }

    // reduce across the 8 row-groups (lanes differing in bits 3..5)
#pragma unroll
    for (int p = 0; p < 4; ++p) {
        a2[p][0] += __shfl_xor(a2[p][0], 8);
        a2[p][1] += __shfl_xor(a2[p][1], 8);
        a2[p][0] += __shfl_xor(a2[p][0], 16);
        a2[p][1] += __shfl_xor(a2[p][1], 16);
        a2[p][0] += __shfl_xor(a2[p][0], 32);
        a2[p][1] += __shfl_xor(a2[p][1], 32);
    }
    float inv = 1.0f / (float)(dg > 1 ? dg : 1);
    if (r8 == 0) {
        us8 o;
#pragma unroll
        for (int b = 0; b < 8; ++b) o[b] = f2bf(a2[b >> 1][b & 1] * inv);
        *(us8*)(agg + (size_t)gid * 64 + cb) = o;
    }
}

// K6 v4: fused MFMA GEMM, 256 rows/block; B in registers; x-half of A staged
// directly from fp32 x via aligned float2 loads (k_convb deleted).
__global__ __launch_bounds__(256) void k_gemm(const ushort_t* __restrict__ agg,
                                              const float* __restrict__ x,
                                              const ushort_t* __restrict__ WT,
                                              const float* __restrict__ bl,
                                              const float* __restrict__ Wc,
                                              const int* __restrict__ batch,
                                              float* __restrict__ gacc) {
    __shared__ ushort_t Alds[64 * 136];   // row stride 136 shorts (pad 8)
    __shared__ float ypart[4][64][2];
    __shared__ float gred[64][2];

    const int t = threadIdx.x;
    const int w = t >> 6;
    const int lane = t & 63;
    const int quad = lane >> 4;
    const int r16 = lane & 15;
    const int brow0 = blockIdx.x * 256;

    if (t < 128) gred[t >> 1][t & 1] = 0.f;

    // B-fragments: wave w covers cols w*64 + 16*ni + r16; k = s*32 + quad*8 .. +7
    s16x8 bfr[4][4];
#pragma unroll
    for (int s = 0; s < 4; ++s)
#pragma unroll
        for (int ni = 0; ni < 4; ++ni)
            bfr[s][ni] = *(const s16x8*)(WT + (size_t)(w * 64 + 16 * ni + r16) * 128
                                            + s * 32 + (quad << 3));

    float blv[4], w0v[4], w1v[4];
#pragma unroll
    for (int ni = 0; ni < 4; ni++) {
        int col = w * 64 + 16 * ni + r16;
        blv[ni] = bl[col];
        w0v[ni] = Wc[col];
        w1v[ni] = Wc[HID + col];
    }

    int lastb = brow0 + 255;
    if (lastb >= N_NODES) lastb = N_NODES - 1;
    const int gmin = clampi(batch[brow0], N_GRAPHS);
    const int gmax = clampi(batch[lastb], N_GRAPHS);
    const int gspan = gmax - gmin + 1;
    const bool use_lds = (gspan <= 64);

    for (int r4 = 0; r4 < 4; ++r4) {
        const int row0 = brow0 + r4 * 64;
        __syncthreads();   // Alds/ypart safe to overwrite (covers gred init on r4==0)
        {
            int row = t >> 2;
            int q4 = t & 3;
            int gr = row0 + row;
            us8* dst = (us8*)&Alds[row * 136 + q4 * 32];
            if (gr < N_NODES) {
                if (q4 < 2) {
                    const us8* src = (const us8*)(agg + (size_t)gr * 64 + (q4 & 1) * 32);
                    dst[0] = src[0]; dst[1] = src[1]; dst[2] = src[2]; dst[3] = src[3];
                } else {
                    // x cols: q4==2 -> 0..31 ; q4==3 -> 32..49 (+zeros)
                    ushort_t tmp[32];
                    if (q4 == 2) {
                        const float2* xp = (const float2*)(x + (size_t)gr * IN_CH);
#pragma unroll
                        for (int j = 0; j < 16; ++j) {
                            float2 f = xp[j];
                            tmp[2 * j] = f2bf(f.x);
                            tmp[2 * j + 1] = f2bf(f.y);
                        }
                    } else {
                        const float2* xp = (const float2*)(x + (size_t)gr * IN_CH + 32);
#pragma unroll
                        for (int j = 0; j < 9; ++j) {
                            float2 f = xp[j];
                            tmp[2 * j] = f2bf(f.x);
                            tmp[2 * j + 1] = f2bf(f.y);
                        }
#pragma unroll
                        for (int j = 18; j < 32; ++j) tmp[j] = 0;
                    }
                    dst[0] = *(const us8*)&tmp[0];
                    dst[1] = *(const us8*)&tmp[8];
                    dst[2] = *(const us8*)&tmp[16];
                    dst[3] = *(const us8*)&tmp[24];
                }
            } else {
                us8 z = {0, 0, 0, 0, 0, 0, 0, 0};
                dst[0] = z; dst[1] = z; dst[2] = z; dst[3] = z;
            }
        }
        __syncthreads();

        f32x4 acc[4][4] = {};
#pragma unroll
        for (int s = 0; s < 4; ++s) {
            s16x8 af[4];
#pragma unroll
            for (int mi = 0; mi < 4; mi++)
                af[mi] = *(const s16x8*)&Alds[(16 * mi + r16) * 136 + s * 32 + (quad << 3)];
#pragma unroll
            for (int mi = 0; mi < 4; mi++)
#pragma unroll
                for (int ni = 0; ni < 4; ni++)
                    acc[mi][ni] = __builtin_amdgcn_mfma_f32_16x16x32_bf16(
                        af[mi], bfr[s][ni], acc[mi][ni], 0, 0, 0);
        }

#pragma unroll
        for (int mi = 0; mi < 4; mi++) {
#pragma unroll
            for (int r = 0; r < 4; r++) {
                float p0 = 0.f, p1 = 0.f;
#pragma unroll
                for (int ni = 0; ni < 4; ni++) {
                    float h = acc[mi][ni][r] + blv[ni];
                    h = (h > 0.f) ? h : 0.01f * h;
                    p0 = fmaf(h, w0v[ni], p0);
                    p1 = fmaf(h, w1v[ni], p1);
                }
#pragma unroll
                for (int off = 1; off < 16; off <<= 1) {
                    p0 += __shfl_xor(p0, off, 16);
                    p1 += __shfl_xor(p1, off, 16);
                }
                if (r16 == 0) {
                    int rl = 16 * mi + (quad << 2) + r;
                    ypart[w][rl][0] = p0;
                    ypart[w][rl][1] = p1;
                }
            }
        }
        __syncthreads();

        if (t < 128) {
            int rl = t >> 1, cc = t & 1;
            int node = row0 + rl;
            if (node < N_NODES) {
                float s = ypart[0][rl][cc] + ypart[1][rl][cc]
                        + ypart[2][rl][cc] + ypart[3][rl][cc];
                int g = clampi(batch[node], N_GRAPHS);
                if (use_lds) atomicAdd(&gred[g - gmin][cc], s);
                else atomicAdd(&gacc[g * 2 + cc], s);
            }
        }
    }
    __syncthreads();
    if (use_lds && t < gspan * 2) {
        int gg = t >> 1, c2 = t & 1;
        float v = gred[gg][c2];
        if (v != 0.f) atomicAdd(&gacc[(gmin + gg) * 2 + c2], v);
    }
}

// K7: finalize (counts from boundary diffs)
__global__ void k_fin(const float* __restrict__ gacc, const int* __restrict__ bnd,
                      const float* __restrict__ bc, float* __restrict__ out) {
    int t = blockIdx.x * blockDim.x + threadIdx.x;
    if (t < N_GRAPHS * 2) {
        int g = t >> 1, c = t & 1;
        int cnt = bnd[g + 1] - bnd[g];
        out[t] = gacc[t] / (float)(cnt > 1 ? cnt : 1) + bc[c];
    }
}

extern "C" void kernel_launch(void* const* d_in, const int* in_sizes, int n_in,
                              void* d_out, int out_size, void* d_ws, size_t ws_size,
                              hipStream_t stream) {
    const float* x  = (const float*)d_in[0];
    const int* ei   = (const int*)d_in[1];
    const int* batch= (const int*)d_in[2];
    const float* Wl = (const float*)d_in[3];
    const float* bl = (const float*)d_in[4];
    const float* Wr = (const float*)d_in[5];
    const float* Wc = (const float*)d_in[6];
    const float* bc = (const float*)d_in[7];
    float* out = (float*)d_out;

    char* ws = (char*)d_ws;
    float* gacc        = (float*)(ws + OFF_GACC);
    int* base          = (int*)(ws + OFF_BASE);
    unsigned int* sd   = (unsigned int*)(ws + OFF_SD);
    int* srcs          = (int*)(ws + OFF_SRC);
    unsigned char* x8  = (unsigned char*)(ws + OFF_X8);
    int* ep            = (int*)(ws + OFF_EP);
    ushort_t* agg      = (ushort_t*)(ws + OFF_EP);   // overlays dead ep
    ushort_t* WT       = (ushort_t*)(ws + OFF_WT);
    int* bnd           = (int*)(ws + OFF_BND);
    ushort_t* lst      = (ushort_t*)(ws + OFF_LST);

    hipMemsetAsync(ws, 0, ZBYTES, stream);
    k_scatter    <<<NBLK2, 512, 0, stream>>>(ei, ep, lst);
    k_colsum     <<<NB, 128, 0, stream>>>(lst, base);
    k_scan_bucket<<<1, 512, 0, stream>>>(base);
    k_csr        <<<NB, 256, 0, stream>>>(ep, lst, base, srcs, sd);
    k_prep       <<<PREP_CONV_BLOCKS + PREP_BW_BLOCKS + PREP_BND_BLOCKS, 256, 0, stream>>>(
                     x, x8, Wl, Wr, WT, batch, bnd);
    k_gather8    <<<(N_NODES + 3) / 4, 256, 0, stream>>>(x8, sd, srcs, agg);
    k_gemm       <<<(N_NODES + 255) / 256, 256, 0, stream>>>(agg, x, WT, bl, Wc, batch, gacc);
    k_fin        <<<4, 256, 0, stream>>>(gacc, bnd, bc, out);
}

// Round 10
// 254.533 us; speedup vs baseline: 1.0438x; 1.0438x over previous
//
#include <hip/hip_runtime.h>

#define N_NODES 100000
#define N_EDGES 3200000
#define N_GRAPHS 512
#define IN_CH 50
#define HID 256
#define NB 391          // buckets of 256 nodes
#define NBLK2 391       // edge blocks (block-local sort)
#define EPB2 8192       // edges per block

typedef unsigned short ushort_t;
using s16x8 = __attribute__((ext_vector_type(8))) short;
using us8   = __attribute__((ext_vector_type(8))) unsigned short;
using us4   = __attribute__((ext_vector_type(4))) unsigned short;
using f32x4 = __attribute__((ext_vector_type(4))) float;
using f32x2 = __attribute__((ext_vector_type(2))) float;

__device__ __forceinline__ float bf2f(ushort_t u) {
    return __uint_as_float(((unsigned int)u) << 16);
}
__device__ __forceinline__ ushort_t f2bf(float f) {
    unsigned int x = __float_as_uint(f);
    unsigned int r = x + 0x7fffu + ((x >> 16) & 1u);
    return (ushort_t)(r >> 16);
}
__device__ __forceinline__ int clampi(int v, int hi) {
    return v < 0 ? 0 : (v >= hi ? hi - 1 : v);
}

// fp8 e4m3fn encode (RNE, saturate to 448) / decode
__device__ __forceinline__ unsigned char f2e4(float f) {
    unsigned char s = (unsigned char)((__float_as_uint(f) >> 31) << 7);
    float a = fabsf(f);
    if (a >= 0.015625f) {
        if (a > 448.f) a = 448.f;
        unsigned int u = __float_as_uint(a);
        u += 0x7FFFFu + ((u >> 20) & 1u);     // RNE into 3-bit mantissa
        int e8 = (int)(u >> 23) - 127 + 7;
        unsigned int m8 = (u >> 20) & 7u;
        if (e8 > 15) { e8 = 15; m8 = 6; }
        return s | (unsigned char)((e8 << 3) | m8);
    } else {
        int m = (int)rintf(a * 512.f);
        if (m > 7) return s | 0x08;
        return s | (unsigned char)m;
    }
}
// branchless e4m3 -> f32: exact for normals AND denormals (bit-place + 2^120 scale)
__device__ __forceinline__ float e42f(unsigned int c) {
    unsigned int w = ((c & 0x80u) << 24) | ((c & 0x7fu) << 20);
    return __uint_as_float(w) * 0x1p120f;
}

// Packed fp8 decode + packed FMA accumulate into f32x2 pairs.
#if __has_builtin(__builtin_amdgcn_cvt_pk_f32_fp8)
#define ACC4(w, m, pb)                                                     \
    do {                                                                   \
        f32x2 p01 = __builtin_amdgcn_cvt_pk_f32_fp8((int)(w), false);      \
        f32x2 p23 = __builtin_amdgcn_cvt_pk_f32_fp8((int)(w), true);       \
        a2[(pb) + 0] = p01 * (m) + a2[(pb) + 0];                           \
        a2[(pb) + 1] = p23 * (m) + a2[(pb) + 1];                           \
    } while (0)
#else
#define ACC4(w, m, pb)                                                     \
    do {                                                                   \
        f32x2 p01, p23;                                                    \
        p01[0] = e42f((w) & 0xffu);        p01[1] = e42f(((w) >> 8) & 0xffu);  \
        p23[0] = e42f(((w) >> 16) & 0xffu); p23[1] = e42f(((w) >> 24) & 0xffu); \
        a2[(pb) + 0] = p01 * (m) + a2[(pb) + 0];                           \
        a2[(pb) + 1] = p23 * (m) + a2[(pb) + 1];                           \
    } while (0)
#endif

// ---- workspace layout (bytes); proven ws_size >= 39,272,064 ----
constexpr size_t OFF_GACC   = 0;          // 512*2*4 = 4096
constexpr size_t OFF_BASE   = 6144;       // (NB+1)*4 = 1568
constexpr size_t ZBYTES     = 8192;       // zeroed prefix
constexpr size_t OFF_SD     = 161536;     // packed (start<<10|deg) u32 [N] = 400000
constexpr size_t OFF_SRC    = 561536;     // int [E] = 12.8MB; xb bf16 [N,64] overlays after gather
constexpr size_t OFF_X8     = 13361536;   // fp8 [N,64] = 6.4MB
constexpr size_t OFF_EP     = 19761536;   // int [391][8192] = 12,812,288; agg bf16 [N,64] overlays
constexpr size_t OFF_WT     = 32573824;   // bf16 [256][128] = 65536 -> 32,639,360
constexpr size_t OFF_BND    = 32639360;   // int [N_GRAPHS+1] = 2052 -> 32,641,412
constexpr size_t OFF_LST    = 32641416;   // u16 [391][392] = 306,544 -> 32,947,960

// P1 v3: block-local counting sort (single pass, no global placement).
__global__ __launch_bounds__(512) void k_scatter(const int* __restrict__ ei,
                                                 int* __restrict__ ep,
                                                 ushort_t* __restrict__ lst) {
    __shared__ int hist[NB];
    __shared__ int sa[512];
    __shared__ int sorig[512];
    __shared__ int lstart[NB + 1];
    __shared__ int lcur[NB];
    __shared__ unsigned int eph[EPB2];

    const int blk = blockIdx.x, t = threadIdx.x;
    for (int i = t; i < NB; i += 512) hist[i] = 0;
    __syncthreads();
    const int e0 = blk * EPB2;
    int sv[16], dv[16];
#pragma unroll
    for (int j = 0; j < 16; ++j) {
        int e = e0 + j * 512 + t;
        if (e < N_EDGES) {
            sv[j] = clampi(ei[e], N_NODES);
            dv[j] = clampi(ei[N_EDGES + e], N_NODES);
        } else {
            dv[j] = -1;
        }
    }
#pragma unroll
    for (int j = 0; j < 16; ++j)
        if (dv[j] >= 0) atomicAdd(&hist[dv[j] >> 8], 1);
    __syncthreads();
    int v = (t < NB) ? hist[t] : 0;
    sa[t] = v; sorig[t] = v;
    __syncthreads();
    for (int off = 1; off < 512; off <<= 1) {
        int u = (t >= off) ? sa[t - off] : 0;
        __syncthreads();
        sa[t] += u;
        __syncthreads();
    }
    if (t < NB) { lstart[t] = sa[t] - sorig[t]; lcur[t] = sa[t] - sorig[t]; }
    if (t == NB - 1) lstart[NB] = sa[t];
    __syncthreads();
#pragma unroll
    for (int j = 0; j < 16; ++j) {
        if (dv[j] >= 0) {
            int b = dv[j] >> 8;
            int r = atomicAdd(&lcur[b], 1);
            eph[r] = ((unsigned int)sv[j] << 8) | (unsigned int)(dv[j] & 255);
        }
    }
    __syncthreads();
    int mv = lstart[NB];
    for (int i = t; i < mv; i += 512) ep[e0 + i] = (int)eph[i];
    for (int i = t; i <= NB; i += 512) lst[blk * (NB + 1) + i] = (ushort_t)lstart[i];
}

// P2a v2: per-bucket totals from the lst table
__global__ __launch_bounds__(128) void k_colsum(const ushort_t* __restrict__ lst,
                                                int* __restrict__ base) {
    __shared__ int part[128];
    int b = blockIdx.x, t = threadIdx.x;
    int s = 0;
    for (int blk = t; blk < NBLK2; blk += 128) {
        int ls = lst[blk * (NB + 1) + b];
        int le = lst[blk * (NB + 1) + b + 1];
        s += le - ls;
    }
    part[t] = s;
    __syncthreads();
    for (int off = 64; off > 0; off >>= 1) {
        if (t < off) part[t] += part[t + off];
        __syncthreads();
    }
    if (t == 0) base[b] = part[0];
}

// P2b: exclusive scan over bucket totals
__global__ __launch_bounds__(512) void k_scan_bucket(int* __restrict__ base) {
    __shared__ int a[512];
    __shared__ int orig[512];
    int t = threadIdx.x;
    int v = (t < NB) ? base[t] : 0;
    orig[t] = v; a[t] = v;
    __syncthreads();
    for (int off = 1; off < 512; off <<= 1) {
        int u = (t >= off) ? a[t - off] : 0;
        __syncthreads();
        a[t] += u;
        __syncthreads();
    }
    if (t < NB) base[t] = a[t] - orig[t];
    if (t == NB - 1) base[NB] = a[t];
}

// P4 v3: per-bucket fine CSR from block-local runs; srcs staged in LDS, flushed coalesced.
#define CSR_CAP 10240
__global__ __launch_bounds__(256) void k_csr(const int* __restrict__ ep,
                                             const ushort_t* __restrict__ lst,
                                             const int* __restrict__ base,
                                             int* __restrict__ srcs,
                                             unsigned int* __restrict__ sd) {
    __shared__ int ldeg[256];
    __shared__ int a[256];
    __shared__ int lcur[256];
    __shared__ int lds_src[CSR_CAP];
    int b = blockIdx.x, t = threadIdx.x;
    int e0 = base[b];
    int m = base[b + 1] - e0;
    ldeg[t] = 0;
    __syncthreads();
    for (int blk = t; blk < NBLK2; blk += 256) {
        int ls = lst[blk * (NB + 1) + b];
        int le = lst[blk * (NB + 1) + b + 1];
        const int* run = ep + blk * EPB2;
        for (int i = ls; i < le; ++i) atomicAdd(&ldeg[run[i] & 255], 1);
    }
    __syncthreads();
    a[t] = ldeg[t];
    __syncthreads();
    for (int off = 1; off < 256; off <<= 1) {
        int u = (t >= off) ? a[t - off] : 0;
        __syncthreads();
        a[t] += u;
        __syncthreads();
    }
    int excl = a[t] - ldeg[t];
    lcur[t] = excl;
    __syncthreads();
    int n = (b << 8) + t;
    if (n < N_NODES) {
        int dgc = ldeg[t] < 1023 ? ldeg[t] : 1023;
        sd[n] = ((unsigned int)(e0 + excl) << 10) | (unsigned int)dgc;
    }
    if (m <= CSR_CAP) {
        for (int blk = t; blk < NBLK2; blk += 256) {
            int ls = lst[blk * (NB + 1) + b];
            int le = lst[blk * (NB + 1) + b + 1];
            const int* run = ep + blk * EPB2;
            for (int i = ls; i < le; ++i) {
                int p = run[i];
                int r = atomicAdd(&lcur[p & 255], 1);
                lds_src[r] = p >> 8;
            }
        }
        __syncthreads();
        for (int i = t; i < m; i += 256) srcs[e0 + i] = lds_src[i];
    } else {
        for (int blk = t; blk < NBLK2; blk += 256) {
            int ls = lst[blk * (NB + 1) + b];
            int le = lst[blk * (NB + 1) + b + 1];
            const int* run = ep + blk * EPB2;
            for (int i = ls; i < le; ++i) {
                int p = run[i];
                int r = atomicAdd(&lcur[p & 255], 1);
                srcs[e0 + r] = p >> 8;
            }
        }
    }
}

// K4 fused prep: [0,25000) conv8 | [25000,25128) buildW | [25128,25519) bounds
#define PREP_CONV_BLOCKS 25000
#define PREP_BW_BLOCKS 128
#define PREP_BND_BLOCKS 391
__global__ __launch_bounds__(256) void k_prep(const float* __restrict__ x,
                                              unsigned char* __restrict__ x8,
                                              const float* __restrict__ Wl,
                                              const float* __restrict__ Wr,
                                              ushort_t* __restrict__ WT,
                                              const int* __restrict__ batch,
                                              int* __restrict__ bnd) {
    int blk = blockIdx.x;
    if (blk < PREP_CONV_BLOCKS) {
        int t = blk * 256 + threadIdx.x;
        int n = t >> 6, c = t & 63;
        x8[t] = (c < IN_CH) ? f2e4(x[n * IN_CH + c]) : (unsigned char)0;
    } else if (blk < PREP_CONV_BLOCKS + PREP_BW_BLOCKS) {
        int idx = (blk - PREP_CONV_BLOCKS) * 256 + threadIdx.x;
        int j = idx >> 7;
        int k = idx & 127;
        ushort_t val = 0;
        if (k < IN_CH) val = f2bf(Wl[j * IN_CH + k]);
        else if (k >= 64 && k < 64 + IN_CH) val = f2bf(Wr[j * IN_CH + (k - 64)]);
        WT[idx] = val;
    } else {
        int n = (blk - PREP_CONV_BLOCKS - PREP_BW_BLOCKS) * 256 + threadIdx.x;
        if (n >= N_NODES) return;
        int b = clampi(batch[n], N_GRAPHS);
        if (n == 0) {
            for (int g = 0; g <= b; ++g) bnd[g] = 0;
        } else {
            int a = clampi(batch[n - 1], N_GRAPHS);
            for (int g = a + 1; g <= b; ++g) bnd[g] = n;
        }
        if (n == N_NODES - 1) {
            for (int g = b + 1; g <= N_GRAPHS; ++g) bnd[g] = N_NODES;
        }
    }
}

// K4d: x fp32 [N,50] -> xb bf16 [N,64] (cols 50..63 = 0); us4-vectorized stores.
// Runs AFTER k_gather8 (overlays dead srcs region).
__global__ __launch_bounds__(256) void k_convb(const float* __restrict__ x,
                                               ushort_t* __restrict__ xb) {
    int t = blockIdx.x * blockDim.x + threadIdx.x;
    if (t >= N_NODES * 16) return;
    int n = t >> 4, c4 = (t & 15) << 2;
    us4 o;
#pragma unroll
    for (int j = 0; j < 4; j++) {
        int c = c4 + j;
        o[j] = (c < IN_CH) ? f2bf(x[n * IN_CH + c]) : (ushort_t)0;
    }
    *(us4*)(xb + (size_t)n * 64 + c4) = o;
}

// K5 v5: wave-per-node gather mean from fp8 x8; packed cvt + packed FMA.
__global__ __launch_bounds__(256) void k_gather8(const unsigned char* __restrict__ x8,
                          const unsigned int* __restrict__ sd,
                          const int* __restrict__ srcs, ushort_t* __restrict__ agg) {
    int gid = (blockIdx.x * blockDim.x + threadIdx.x) >> 6;
    int lane = threadIdx.x & 63;
    if (gid >= N_NODES) return;
    int r8 = lane >> 3;          // row within group of 8
    int c8 = lane & 7;           // byte-octet within 64B row
    unsigned int v = sd[gid];
    int dg = (int)(v & 1023u);
    int st = (int)(v >> 10);

    f32x2 a2[4] = {};            // 8 channels as 4 packed pairs

    const int nit = (dg + 31) >> 5;
    const int cb = c8 << 3;      // byte offset within row
    for (int it = 0; it < nit; ++it) {
        int i0 = (it << 5) + r8;
        int i1 = i0 + 8, i2 = i0 + 16, i3 = i0 + 24;
        int s0 = srcs[st + (i0 < dg ? i0 : 0)];
        int s1 = srcs[st + (i1 < dg ? i1 : 0)];
        int s2 = srcs[st + (i2 < dg ? i2 : 0)];
        int s3 = srcs[st + (i3 < dg ? i3 : 0)];
        uint2 w0 = *(const uint2*)(x8 + (size_t)s0 * 64 + cb);
        uint2 w1 = *(const uint2*)(x8 + (size_t)s1 * 64 + cb);
        uint2 w2 = *(const uint2*)(x8 + (size_t)s2 * 64 + cb);
        uint2 w3 = *(const uint2*)(x8 + (size_t)s3 * 64 + cb);
        float m0 = i0 < dg ? 1.f : 0.f;
        float m1 = i1 < dg ? 1.f : 0.f;
        float m2 = i2 < dg ? 1.f : 0.f;
        float m3 = i3 < dg ? 1.f : 0.f;
        ACC4(w0.x, m0, 0); ACC4(w0.y, m0, 2);
        ACC4(w1.x, m1, 0); ACC4(w1.y, m1, 2);
        ACC4(w2.x, m2, 0); ACC4(w2.y, m2, 2);
        ACC4(w3.x, m3, 0); ACC4(w3.y, m3, 2);
    }

    // reduce across the 8 row-groups (lanes differing in bits 3..5)
#pragma unroll
    for (int p = 0; p < 4; ++p) {
        a2[p][0] += __shfl_xor(a2[p][0], 8);
        a2[p][1] += __shfl_xor(a2[p][1], 8);
        a2[p][0] += __shfl_xor(a2[p][0], 16);
        a2[p][1] += __shfl_xor(a2[p][1], 16);
        a2[p][0] += __shfl_xor(a2[p][0], 32);
        a2[p][1] += __shfl_xor(a2[p][1], 32);
    }
    float inv = 1.0f / (float)(dg > 1 ? dg : 1);
    if (r8 == 0) {
        us8 o;
#pragma unroll
        for (int b = 0; b < 8; ++b) o[b] = f2bf(a2[b >> 1][b & 1] * inv);
        *(us8*)(agg + (size_t)gid * 64 + cb) = o;
    }
}

// K6 v5: fused MFMA GEMM, 128 rows/block (782 blocks, 2 rounds).
// B in registers; A staged as pure us8 copies from agg + xb (conversion-free).
__global__ __launch_bounds__(256) void k_gemm(const ushort_t* __restrict__ agg,
                                              const ushort_t* __restrict__ xb,
                                              const ushort_t* __restrict__ WT,
                                              const float* __restrict__ bl,
                                              const float* __restrict__ Wc,
                                              const int* __restrict__ batch,
                                              float* __restrict__ gacc) {
    __shared__ ushort_t Alds[64 * 136];   // row stride 136 shorts (pad 8)
    __shared__ float ypart[4][64][2];
    __shared__ float gred[64][2];

    const int t = threadIdx.x;
    const int w = t >> 6;
    const int lane = t & 63;
    const int quad = lane >> 4;
    const int r16 = lane & 15;
    const int brow0 = blockIdx.x * 128;

    if (t < 128) gred[t >> 1][t & 1] = 0.f;

    // B-fragments: wave w covers cols w*64 + 16*ni + r16; k = s*32 + quad*8 .. +7
    s16x8 bfr[4][4];
#pragma unroll
    for (int s = 0; s < 4; ++s)
#pragma unroll
        for (int ni = 0; ni < 4; ++ni)
            bfr[s][ni] = *(const s16x8*)(WT + (size_t)(w * 64 + 16 * ni + r16) * 128
                                            + s * 32 + (quad << 3));

    float blv[4], w0v[4], w1v[4];
#pragma unroll
    for (int ni = 0; ni < 4; ni++) {
        int col = w * 64 + 16 * ni + r16;
        blv[ni] = bl[col];
        w0v[ni] = Wc[col];
        w1v[ni] = Wc[HID + col];
    }

    int lastb = brow0 + 127;
    if (lastb >= N_NODES) lastb = N_NODES - 1;
    const int gmin = clampi(batch[brow0], N_GRAPHS);
    const int gmax = clampi(batch[lastb], N_GRAPHS);
    const int gspan = gmax - gmin + 1;
    const bool use_lds = (gspan <= 64);

    for (int r4 = 0; r4 < 2; ++r4) {
        const int row0 = brow0 + r4 * 64;
        __syncthreads();   // Alds/ypart safe to overwrite (covers gred init on r4==0)
        {
            int row = t >> 2;
            int q4 = t & 3;
            int gr = row0 + row;
            us8* dst = (us8*)&Alds[row * 136 + q4 * 32];
            if (gr < N_NODES) {
                const us8* src = (q4 < 2)
                    ? (const us8*)(agg + (size_t)gr * 64 + (q4 & 1) * 32)
                    : (const us8*)(xb + (size_t)gr * 64 + (q4 & 1) * 32);
                dst[0] = src[0];
                dst[1] = src[1];
                dst[2] = src[2];
                dst[3] = src[3];
            } else {
                us8 z = {0, 0, 0, 0, 0, 0, 0, 0};
                dst[0] = z; dst[1] = z; dst[2] = z; dst[3] = z;
            }
        }
        __syncthreads();

        f32x4 acc[4][4] = {};
#pragma unroll
        for (int s = 0; s < 4; ++s) {
            s16x8 af[4];
#pragma unroll
            for (int mi = 0; mi < 4; mi++)
                af[mi] = *(const s16x8*)&Alds[(16 * mi + r16) * 136 + s * 32 + (quad << 3)];
#pragma unroll
            for (int mi = 0; mi < 4; mi++)
#pragma unroll
                for (int ni = 0; ni < 4; ni++)
                    acc[mi][ni] = __builtin_amdgcn_mfma_f32_16x16x32_bf16(
                        af[mi], bfr[s][ni], acc[mi][ni], 0, 0, 0);
        }

#pragma unroll
        for (int mi = 0; mi < 4; mi++) {
#pragma unroll
            for (int r = 0; r < 4; r++) {
                float p0 = 0.f, p1 = 0.f;
#pragma unroll
                for (int ni = 0; ni < 4; ni++) {
                    float h = acc[mi][ni][r] + blv[ni];
                    h = (h > 0.f) ? h : 0.01f * h;
                    p0 = fmaf(h, w0v[ni], p0);
                    p1 = fmaf(h, w1v[ni], p1);
                }
#pragma unroll
                for (int off = 1; off < 16; off <<= 1) {
                    p0 += __shfl_xor(p0, off, 16);
                    p1 += __shfl_xor(p1, off, 16);
                }
                if (r16 == 0) {
                    int rl = 16 * mi + (quad << 2) + r;
                    ypart[w][rl][0] = p0;
                    ypart[w][rl][1] = p1;
                }
            }
        }
        __syncthreads();

        if (t < 128) {
            int rl = t >> 1, cc = t & 1;
            int node = row0 + rl;
            if (node < N_NODES) {
                float s = ypart[0][rl][cc] + ypart[1][rl][cc]
                        + ypart[2][rl][cc] + ypart[3][rl][cc];
                int g = clampi(batch[node], N_GRAPHS);
                if (use_lds) atomicAdd(&gred[g - gmin][cc], s);
                else atomicAdd(&gacc[g * 2 + cc], s);
            }
        }
    }
    __syncthreads();
    if (use_lds && t < gspan * 2) {
        int gg = t >> 1, c2 = t & 1;
        float v = gred[gg][c2];
        if (v != 0.f) atomicAdd(&gacc[(gmin + gg) * 2 + c2], v);
    }
}

// K7: finalize (counts from boundary diffs)
__global__ void k_fin(const float* __restrict__ gacc, const int* __restrict__ bnd,
                      const float* __restrict__ bc, float* __restrict__ out) {
    int t = blockIdx.x * blockDim.x + threadIdx.x;
    if (t < N_GRAPHS * 2) {
        int g = t >> 1, c = t & 1;
        int cnt = bnd[g + 1] - bnd[g];
        out[t] = gacc[t] / (float)(cnt > 1 ? cnt : 1) + bc[c];
    }
}

extern "C" void kernel_launch(void* const* d_in, const int* in_sizes, int n_in,
                              void* d_out, int out_size, void* d_ws, size_t ws_size,
                              hipStream_t stream) {
    const float* x  = (const float*)d_in[0];
    const int* ei   = (const int*)d_in[1];
    const int* batch= (const int*)d_in[2];
    const float* Wl = (const float*)d_in[3];
    const float* bl = (const float*)d_in[4];
    const float* Wr = (const float*)d_in[5];
    const float* Wc = (const float*)d_in[6];
    const float* bc = (const float*)d_in[7];
    float* out = (float*)d_out;

    char* ws = (char*)d_ws;
    float* gacc        = (float*)(ws + OFF_GACC);
    int* base          = (int*)(ws + OFF_BASE);
    unsigned int* sd   = (unsigned int*)(ws + OFF_SD);
    int* srcs          = (int*)(ws + OFF_SRC);
    ushort_t* xb       = (ushort_t*)(ws + OFF_SRC);  // overlays srcs after gather
    unsigned char* x8  = (unsigned char*)(ws + OFF_X8);
    int* ep            = (int*)(ws + OFF_EP);
    ushort_t* agg      = (ushort_t*)(ws + OFF_EP);   // overlays dead ep
    ushort_t* WT       = (ushort_t*)(ws + OFF_WT);
    int* bnd           = (int*)(ws + OFF_BND);
    ushort_t* lst      = (ushort_t*)(ws + OFF_LST);

    hipMemsetAsync(ws, 0, ZBYTES, stream);
    k_scatter    <<<NBLK2, 512, 0, stream>>>(ei, ep, lst);
    k_colsum     <<<NB, 128, 0, stream>>>(lst, base);
    k_scan_bucket<<<1, 512, 0, stream>>>(base);
    k_csr        <<<NB, 256, 0, stream>>>(ep, lst, base, srcs, sd);
    k_prep       <<<PREP_CONV_BLOCKS + PREP_BW_BLOCKS + PREP_BND_BLOCKS, 256, 0, stream>>>(
                     x, x8, Wl, Wr, WT, batch, bnd);
    k_gather8    <<<(N_NODES + 3) / 4, 256, 0, stream>>>(x8, sd, srcs, agg);
    k_convb      <<<(N_NODES * 16 + 255) / 256, 256, 0, stream>>>(x, xb);
    k_gemm       <<<(N_NODES + 127) / 128, 256, 0, stream>>>(agg, xb, WT, bl, Wc, batch, gacc);
    k_fin        <<<4, 256, 0, stream>>>(gacc, bnd, bc, out);
}

// Round 11
// 228.804 us; speedup vs baseline: 1.1612x; 1.1124x over previous
//
#include <hip/hip_runtime.h>

#define N_NODES 100000
#define N_EDGES 3200000
#define N_GRAPHS 512
#define IN_CH 50
#define HID 256
#define NB 391          // buckets of 256 nodes
#define NBLK2 391       // edge blocks (block-local sort)
#define EPB2 8192       // edges per block

typedef unsigned short ushort_t;
using s16x8 = __attribute__((ext_vector_type(8))) short;
using us8   = __attribute__((ext_vector_type(8))) unsigned short;
using us4   = __attribute__((ext_vector_type(4))) unsigned short;
using f32x4 = __attribute__((ext_vector_type(4))) float;
using f32x2 = __attribute__((ext_vector_type(2))) float;

__device__ __forceinline__ float bf2f(ushort_t u) {
    return __uint_as_float(((unsigned int)u) << 16);
}
__device__ __forceinline__ ushort_t f2bf(float f) {
    unsigned int x = __float_as_uint(f);
    unsigned int r = x + 0x7fffu + ((x >> 16) & 1u);
    return (ushort_t)(r >> 16);
}
__device__ __forceinline__ int clampi(int v, int hi) {
    return v < 0 ? 0 : (v >= hi ? hi - 1 : v);
}

// fp8 e4m3fn encode (RNE, saturate to 448) / decode
__device__ __forceinline__ unsigned char f2e4(float f) {
    unsigned char s = (unsigned char)((__float_as_uint(f) >> 31) << 7);
    float a = fabsf(f);
    if (a >= 0.015625f) {
        if (a > 448.f) a = 448.f;
        unsigned int u = __float_as_uint(a);
        u += 0x7FFFFu + ((u >> 20) & 1u);     // RNE into 3-bit mantissa
        int e8 = (int)(u >> 23) - 127 + 7;
        unsigned int m8 = (u >> 20) & 7u;
        if (e8 > 15) { e8 = 15; m8 = 6; }
        return s | (unsigned char)((e8 << 3) | m8);
    } else {
        int m = (int)rintf(a * 512.f);
        if (m > 7) return s | 0x08;
        return s | (unsigned char)m;
    }
}
// branchless e4m3 -> f32: exact for normals AND denormals (bit-place + 2^120 scale)
__device__ __forceinline__ float e42f(unsigned int c) {
    unsigned int w = ((c & 0x80u) << 24) | ((c & 0x7fu) << 20);
    return __uint_as_float(w) * 0x1p120f;
}

// Packed fp8 decode + packed FMA accumulate into f32x2 pairs.
#if __has_builtin(__builtin_amdgcn_cvt_pk_f32_fp8)
#define ACC4(w, m, pb)                                                     \
    do {                                                                   \
        f32x2 p01 = __builtin_amdgcn_cvt_pk_f32_fp8((int)(w), false);      \
        f32x2 p23 = __builtin_amdgcn_cvt_pk_f32_fp8((int)(w), true);       \
        a2[(pb) + 0] = p01 * (m) + a2[(pb) + 0];                           \
        a2[(pb) + 1] = p23 * (m) + a2[(pb) + 1];                           \
    } while (0)
#else
#define ACC4(w, m, pb)                                                     \
    do {                                                                   \
        f32x2 p01, p23;                                                    \
        p01[0] = e42f((w) & 0xffu);        p01[1] = e42f(((w) >> 8) & 0xffu);  \
        p23[0] = e42f(((w) >> 16) & 0xffu); p23[1] = e42f(((w) >> 24) & 0xffu); \
        a2[(pb) + 0] = p01 * (m) + a2[(pb) + 0];                           \
        a2[(pb) + 1] = p23 * (m) + a2[(pb) + 1];                           \
    } while (0)
#endif

// ---- workspace layout (bytes); proven ws_size >= 39,272,064 ----
constexpr size_t OFF_GACC   = 0;          // 512*2*4 = 4096
constexpr size_t OFF_BASE   = 6144;       // (NB+1)*4 = 1568
constexpr size_t ZBYTES     = 8192;       // zeroed prefix
constexpr size_t OFF_SD     = 161536;     // packed (start<<10|deg) u32 [N] = 400000
constexpr size_t OFF_SRC    = 561536;     // int [E] = 12.8MB; xb bf16 [N,64] overlays after gather
constexpr size_t OFF_X8     = 13361536;   // fp8 [N,64] = 6.4MB
constexpr size_t OFF_EP     = 19761536;   // int [391][8192] = 12,812,288; agg bf16 [N,64] overlays
constexpr size_t OFF_WT     = 32573824;   // bf16 [256][128] = 65536 -> 32,639,360
constexpr size_t OFF_BND    = 32639360;   // int [N_GRAPHS+1] = 2052 -> 32,641,412
constexpr size_t OFF_LST    = 32641416;   // u16 [391][392] = 306,544 -> 32,947,960

// P1 v3: block-local counting sort (single pass, no global placement).
__global__ __launch_bounds__(512) void k_scatter(const int* __restrict__ ei,
                                                 int* __restrict__ ep,
                                                 ushort_t* __restrict__ lst) {
    __shared__ int hist[NB];
    __shared__ int sa[512];
    __shared__ int sorig[512];
    __shared__ int lstart[NB + 1];
    __shared__ int lcur[NB];
    __shared__ unsigned int eph[EPB2];

    const int blk = blockIdx.x, t = threadIdx.x;
    for (int i = t; i < NB; i += 512) hist[i] = 0;
    __syncthreads();
    const int e0 = blk * EPB2;
    int sv[16], dv[16];
#pragma unroll
    for (int j = 0; j < 16; ++j) {
        int e = e0 + j * 512 + t;
        if (e < N_EDGES) {
            sv[j] = clampi(ei[e], N_NODES);
            dv[j] = clampi(ei[N_EDGES + e], N_NODES);
        } else {
            dv[j] = -1;
        }
    }
#pragma unroll
    for (int j = 0; j < 16; ++j)
        if (dv[j] >= 0) atomicAdd(&hist[dv[j] >> 8], 1);
    __syncthreads();
    int v = (t < NB) ? hist[t] : 0;
    sa[t] = v; sorig[t] = v;
    __syncthreads();
    for (int off = 1; off < 512; off <<= 1) {
        int u = (t >= off) ? sa[t - off] : 0;
        __syncthreads();
        sa[t] += u;
        __syncthreads();
    }
    if (t < NB) { lstart[t] = sa[t] - sorig[t]; lcur[t] = sa[t] - sorig[t]; }
    if (t == NB - 1) lstart[NB] = sa[t];
    __syncthreads();
#pragma unroll
    for (int j = 0; j < 16; ++j) {
        if (dv[j] >= 0) {
            int b = dv[j] >> 8;
            int r = atomicAdd(&lcur[b], 1);
            eph[r] = ((unsigned int)sv[j] << 8) | (unsigned int)(dv[j] & 255);
        }
    }
    __syncthreads();
    int mv = lstart[NB];
    for (int i = t; i < mv; i += 512) ep[e0 + i] = (int)eph[i];
    for (int i = t; i <= NB; i += 512) lst[blk * (NB + 1) + i] = (ushort_t)lstart[i];
}

// P2a v2: per-bucket totals from the lst table
__global__ __launch_bounds__(128) void k_colsum(const ushort_t* __restrict__ lst,
                                                int* __restrict__ base) {
    __shared__ int part[128];
    int b = blockIdx.x, t = threadIdx.x;
    int s = 0;
    for (int blk = t; blk < NBLK2; blk += 128) {
        int ls = lst[blk * (NB + 1) + b];
        int le = lst[blk * (NB + 1) + b + 1];
        s += le - ls;
    }
    part[t] = s;
    __syncthreads();
    for (int off = 64; off > 0; off >>= 1) {
        if (t < off) part[t] += part[t + off];
        __syncthreads();
    }
    if (t == 0) base[b] = part[0];
}

// P2b: exclusive scan over bucket totals
__global__ __launch_bounds__(512) void k_scan_bucket(int* __restrict__ base) {
    __shared__ int a[512];
    __shared__ int orig[512];
    int t = threadIdx.x;
    int v = (t < NB) ? base[t] : 0;
    orig[t] = v; a[t] = v;
    __syncthreads();
    for (int off = 1; off < 512; off <<= 1) {
        int u = (t >= off) ? a[t - off] : 0;
        __syncthreads();
        a[t] += u;
        __syncthreads();
    }
    if (t < NB) base[t] = a[t] - orig[t];
    if (t == NB - 1) base[NB] = a[t];
}

// P4 v4: per-bucket fine CSR, latency-optimized.
// Runs gathered ONCE into LDS via a flattened fully-independent copy
// (runof[] run-id map -> one global-latency round for all ~8184 edges),
// then histogram/scan/placement run out of LDS. Placement writes srcs
// directly (random 4B within 32KB window = L2-absorbed, R8 lesson).
#define CSR_CAP 10240
__global__ __launch_bounds__(512) void k_csr(const int* __restrict__ ep,
                                             const ushort_t* __restrict__ lst,
                                             const int* __restrict__ base,
                                             int* __restrict__ srcs,
                                             unsigned int* __restrict__ sd) {
    __shared__ int sa[512];
    __shared__ int sorig[512];
    __shared__ int rro[NBLK2 + 1];   // exclusive offsets of runs within bucket
    __shared__ int lsa[NBLK2];       // run start within source block
    __shared__ ushort_t runof[CSR_CAP];
    __shared__ int lds_ep[CSR_CAP];
    __shared__ int ldeg[256];
    __shared__ int aa[256];
    __shared__ int lcur[256];

    const int b = blockIdx.x, t = threadIdx.x;
    const int e0 = base[b];

    // 1. per-run length + start (one uncoalesced round; thread t <-> block t)
    int lenv = 0, lsv = 0;
    if (t < NBLK2) {
        lsv = (int)lst[t * (NB + 1) + b];
        int le = (int)lst[t * (NB + 1) + b + 1];
        lenv = le - lsv;
        lsa[t] = lsv;
    }
    sa[t] = lenv; sorig[t] = lenv;
    __syncthreads();
    for (int off = 1; off < 512; off <<= 1) {
        int u = (t >= off) ? sa[t - off] : 0;
        __syncthreads();
        sa[t] += u;
        __syncthreads();
    }
    if (t < NBLK2) rro[t] = sa[t] - sorig[t];
    if (t == NBLK2 - 1) rro[NBLK2] = sa[t];
    __syncthreads();
    const int m = rro[NBLK2];

    if (m <= CSR_CAP) {
        // 2. run-id map (cheap serial LDS stores)
        if (t < NBLK2) {
            int o = rro[t];
            for (int j = 0; j < lenv; ++j) runof[o + j] = (ushort_t)t;
        }
        if (t < 256) ldeg[t] = 0;
        __syncthreads();
        // 3. flattened copy: all iterations independent -> one latency round
        for (int i = t; i < m; i += 512) {
            int r = (int)runof[i];
            lds_ep[i] = ep[r * EPB2 + lsa[r] + (i - rro[r])];
        }
        __syncthreads();
        // 4. histogram from LDS
        for (int i = t; i < m; i += 512) atomicAdd(&ldeg[lds_ep[i] & 255], 1);
        __syncthreads();
        // 5. scan ldeg (256 entries, 512 threads)
        if (t < 256) aa[t] = ldeg[t];
        __syncthreads();
        for (int off = 1; off < 256; off <<= 1) {
            int u = (t >= off && t < 256) ? aa[t - off] : 0;
            __syncthreads();
            if (t < 256) aa[t] += u;
            __syncthreads();
        }
        if (t < 256) {
            int excl = aa[t] - ldeg[t];
            lcur[t] = excl;
            int n = (b << 8) + t;
            if (n < N_NODES) {
                int dgc = ldeg[t] < 1023 ? ldeg[t] : 1023;
                sd[n] = ((unsigned int)(e0 + excl) << 10) | (unsigned int)dgc;
            }
        }
        __syncthreads();
        // 6. placement: direct global stores (L2-absorbed)
        for (int i = t; i < m; i += 512) {
            int p = lds_ep[i];
            int r = atomicAdd(&lcur[p & 255], 1);
            srcs[e0 + r] = p >> 8;
        }
    } else {
        // fallback (statistically never): two-pass over scattered runs
        if (t < 256) ldeg[t] = 0;
        __syncthreads();
        for (int blk = t; blk < NBLK2; blk += 512) {
            int ls = (int)lst[blk * (NB + 1) + b];
            int le = (int)lst[blk * (NB + 1) + b + 1];
            const int* run = ep + blk * EPB2;
            for (int i = ls; i < le; ++i) atomicAdd(&ldeg[run[i] & 255], 1);
        }
        __syncthreads();
        if (t < 256) aa[t] = ldeg[t];
        __syncthreads();
        for (int off = 1; off < 256; off <<= 1) {
            int u = (t >= off && t < 256) ? aa[t - off] : 0;
            __syncthreads();
            if (t < 256) aa[t] += u;
            __syncthreads();
        }
        if (t < 256) {
            int excl = aa[t] - ldeg[t];
            lcur[t] = excl;
            int n = (b << 8) + t;
            if (n < N_NODES) {
                int dgc = ldeg[t] < 1023 ? ldeg[t] : 1023;
                sd[n] = ((unsigned int)(e0 + excl) << 10) | (unsigned int)dgc;
            }
        }
        __syncthreads();
        for (int blk = t; blk < NBLK2; blk += 512) {
            int ls = (int)lst[blk * (NB + 1) + b];
            int le = (int)lst[blk * (NB + 1) + b + 1];
            const int* run = ep + blk * EPB2;
            for (int i = ls; i < le; ++i) {
                int p = run[i];
                int r = atomicAdd(&lcur[p & 255], 1);
                srcs[e0 + r] = p >> 8;
            }
        }
    }
}

// K4 fused prep: [0,25000) conv8 | [25000,25128) buildW | [25128,25519) bounds
#define PREP_CONV_BLOCKS 25000
#define PREP_BW_BLOCKS 128
#define PREP_BND_BLOCKS 391
__global__ __launch_bounds__(256) void k_prep(const float* __restrict__ x,
                                              unsigned char* __restrict__ x8,
                                              const float* __restrict__ Wl,
                                              const float* __restrict__ Wr,
                                              ushort_t* __restrict__ WT,
                                              const int* __restrict__ batch,
                                              int* __restrict__ bnd) {
    int blk = blockIdx.x;
    if (blk < PREP_CONV_BLOCKS) {
        int t = blk * 256 + threadIdx.x;
        int n = t >> 6, c = t & 63;
        x8[t] = (c < IN_CH) ? f2e4(x[n * IN_CH + c]) : (unsigned char)0;
    } else if (blk < PREP_CONV_BLOCKS + PREP_BW_BLOCKS) {
        int idx = (blk - PREP_CONV_BLOCKS) * 256 + threadIdx.x;
        int j = idx >> 7;
        int k = idx & 127;
        ushort_t val = 0;
        if (k < IN_CH) val = f2bf(Wl[j * IN_CH + k]);
        else if (k >= 64 && k < 64 + IN_CH) val = f2bf(Wr[j * IN_CH + (k - 64)]);
        WT[idx] = val;
    } else {
        int n = (blk - PREP_CONV_BLOCKS - PREP_BW_BLOCKS) * 256 + threadIdx.x;
        if (n >= N_NODES) return;
        int b = clampi(batch[n], N_GRAPHS);
        if (n == 0) {
            for (int g = 0; g <= b; ++g) bnd[g] = 0;
        } else {
            int a = clampi(batch[n - 1], N_GRAPHS);
            for (int g = a + 1; g <= b; ++g) bnd[g] = n;
        }
        if (n == N_NODES - 1) {
            for (int g = b + 1; g <= N_GRAPHS; ++g) bnd[g] = N_NODES;
        }
    }
}

// K4d: x fp32 [N,50] -> xb bf16 [N,64] (cols 50..63 = 0); us4-vectorized stores.
// Runs AFTER k_gather8 (overlays dead srcs region).
__global__ __launch_bounds__(256) void k_convb(const float* __restrict__ x,
                                               ushort_t* __restrict__ xb) {
    int t = blockIdx.x * blockDim.x + threadIdx.x;
    if (t >= N_NODES * 16) return;
    int n = t >> 4, c4 = (t & 15) << 2;
    us4 o;
#pragma unroll
    for (int j = 0; j < 4; j++) {
        int c = c4 + j;
        o[j] = (c < IN_CH) ? f2bf(x[n * IN_CH + c]) : (ushort_t)0;
    }
    *(us4*)(xb + (size_t)n * 64 + c4) = o;
}

// K5 v5: wave-per-node gather mean from fp8 x8; packed cvt + packed FMA.
__global__ __launch_bounds__(256) void k_gather8(const unsigned char* __restrict__ x8,
                          const unsigned int* __restrict__ sd,
                          const int* __restrict__ srcs, ushort_t* __restrict__ agg) {
    int gid = (blockIdx.x * blockDim.x + threadIdx.x) >> 6;
    int lane = threadIdx.x & 63;
    if (gid >= N_NODES) return;
    int r8 = lane >> 3;          // row within group of 8
    int c8 = lane & 7;           // byte-octet within 64B row
    unsigned int v = sd[gid];
    int dg = (int)(v & 1023u);
    int st = (int)(v >> 10);

    f32x2 a2[4] = {};            // 8 channels as 4 packed pairs

    const int nit = (dg + 31) >> 5;
    const int cb = c8 << 3;      // byte offset within row
    for (int it = 0; it < nit; ++it) {
        int i0 = (it << 5) + r8;
        int i1 = i0 + 8, i2 = i0 + 16, i3 = i0 + 24;
        int s0 = srcs[st + (i0 < dg ? i0 : 0)];
        int s1 = srcs[st + (i1 < dg ? i1 : 0)];
        int s2 = srcs[st + (i2 < dg ? i2 : 0)];
        int s3 = srcs[st + (i3 < dg ? i3 : 0)];
        uint2 w0 = *(const uint2*)(x8 + (size_t)s0 * 64 + cb);
        uint2 w1 = *(const uint2*)(x8 + (size_t)s1 * 64 + cb);
        uint2 w2 = *(const uint2*)(x8 + (size_t)s2 * 64 + cb);
        uint2 w3 = *(const uint2*)(x8 + (size_t)s3 * 64 + cb);
        float m0 = i0 < dg ? 1.f : 0.f;
        float m1 = i1 < dg ? 1.f : 0.f;
        float m2 = i2 < dg ? 1.f : 0.f;
        float m3 = i3 < dg ? 1.f : 0.f;
        ACC4(w0.x, m0, 0); ACC4(w0.y, m0, 2);
        ACC4(w1.x, m1, 0); ACC4(w1.y, m1, 2);
        ACC4(w2.x, m2, 0); ACC4(w2.y, m2, 2);
        ACC4(w3.x, m3, 0); ACC4(w3.y, m3, 2);
    }

    // reduce across the 8 row-groups (lanes differing in bits 3..5)
#pragma unroll
    for (int p = 0; p < 4; ++p) {
        a2[p][0] += __shfl_xor(a2[p][0], 8);
        a2[p][1] += __shfl_xor(a2[p][1], 8);
        a2[p][0] += __shfl_xor(a2[p][0], 16);
        a2[p][1] += __shfl_xor(a2[p][1], 16);
        a2[p][0] += __shfl_xor(a2[p][0], 32);
        a2[p][1] += __shfl_xor(a2[p][1], 32);
    }
    float inv = 1.0f / (float)(dg > 1 ? dg : 1);
    if (r8 == 0) {
        us8 o;
#pragma unroll
        for (int b = 0; b < 8; ++b) o[b] = f2bf(a2[b >> 1][b & 1] * inv);
        *(us8*)(agg + (size_t)gid * 64 + cb) = o;
    }
}

// K6 v5: fused MFMA GEMM, 128 rows/block (782 blocks, 2 rounds).
// B in registers; A staged as pure us8 copies from agg + xb (conversion-free).
__global__ __launch_bounds__(256) void k_gemm(const ushort_t* __restrict__ agg,
                                              const ushort_t* __restrict__ xb,
                                              const ushort_t* __restrict__ WT,
                                              const float* __restrict__ bl,
                                              const float* __restrict__ Wc,
                                              const int* __restrict__ batch,
                                              float* __restrict__ gacc) {
    __shared__ ushort_t Alds[64 * 136];   // row stride 136 shorts (pad 8)
    __shared__ float ypart[4][64][2];
    __shared__ float gred[64][2];

    const int t = threadIdx.x;
    const int w = t >> 6;
    const int lane = t & 63;
    const int quad = lane >> 4;
    const int r16 = lane & 15;
    const int brow0 = blockIdx.x * 128;

    if (t < 128) gred[t >> 1][t & 1] = 0.f;

    // B-fragments: wave w covers cols w*64 + 16*ni + r16; k = s*32 + quad*8 .. +7
    s16x8 bfr[4][4];
#pragma unroll
    for (int s = 0; s < 4; ++s)
#pragma unroll
        for (int ni = 0; ni < 4; ++ni)
            bfr[s][ni] = *(const s16x8*)(WT + (size_t)(w * 64 + 16 * ni + r16) * 128
                                            + s * 32 + (quad << 3));

    float blv[4], w0v[4], w1v[4];
#pragma unroll
    for (int ni = 0; ni < 4; ni++) {
        int col = w * 64 + 16 * ni + r16;
        blv[ni] = bl[col];
        w0v[ni] = Wc[col];
        w1v[ni] = Wc[HID + col];
    }

    int lastb = brow0 + 127;
    if (lastb >= N_NODES) lastb = N_NODES - 1;
    const int gmin = clampi(batch[brow0], N_GRAPHS);
    const int gmax = clampi(batch[lastb], N_GRAPHS);
    const int gspan = gmax - gmin + 1;
    const bool use_lds = (gspan <= 64);

    for (int r4 = 0; r4 < 2; ++r4) {
        const int row0 = brow0 + r4 * 64;
        __syncthreads();   // Alds/ypart safe to overwrite (covers gred init on r4==0)
        {
            int row = t >> 2;
            int q4 = t & 3;
            int gr = row0 + row;
            us8* dst = (us8*)&Alds[row * 136 + q4 * 32];
            if (gr < N_NODES) {
                const us8* src = (q4 < 2)
                    ? (const us8*)(agg + (size_t)gr * 64 + (q4 & 1) * 32)
                    : (const us8*)(xb + (size_t)gr * 64 + (q4 & 1) * 32);
                dst[0] = src[0];
                dst[1] = src[1];
                dst[2] = src[2];
                dst[3] = src[3];
            } else {
                us8 z = {0, 0, 0, 0, 0, 0, 0, 0};
                dst[0] = z; dst[1] = z; dst[2] = z; dst[3] = z;
            }
        }
        __syncthreads();

        f32x4 acc[4][4] = {};
#pragma unroll
        for (int s = 0; s < 4; ++s) {
            s16x8 af[4];
#pragma unroll
            for (int mi = 0; mi < 4; mi++)
                af[mi] = *(const s16x8*)&Alds[(16 * mi + r16) * 136 + s * 32 + (quad << 3)];
#pragma unroll
            for (int mi = 0; mi < 4; mi++)
#pragma unroll
                for (int ni = 0; ni < 4; ni++)
                    acc[mi][ni] = __builtin_amdgcn_mfma_f32_16x16x32_bf16(
                        af[mi], bfr[s][ni], acc[mi][ni], 0, 0, 0);
        }

#pragma unroll
        for (int mi = 0; mi < 4; mi++) {
#pragma unroll
            for (int r = 0; r < 4; r++) {
                float p0 = 0.f, p1 = 0.f;
#pragma unroll
                for (int ni = 0; ni < 4; ni++) {
                    float h = acc[mi][ni][r] + blv[ni];
                    h = (h > 0.f) ? h : 0.01f * h;
                    p0 = fmaf(h, w0v[ni], p0);
                    p1 = fmaf(h, w1v[ni], p1);
                }
#pragma unroll
                for (int off = 1; off < 16; off <<= 1) {
                    p0 += __shfl_xor(p0, off, 16);
                    p1 += __shfl_xor(p1, off, 16);
                }
                if (r16 == 0) {
                    int rl = 16 * mi + (quad << 2) + r;
                    ypart[w][rl][0] = p0;
                    ypart[w][rl][1] = p1;
                }
            }
        }
        __syncthreads();

        if (t < 128) {
            int rl = t >> 1, cc = t & 1;
            int node = row0 + rl;
            if (node < N_NODES) {
                float s = ypart[0][rl][cc] + ypart[1][rl][cc]
                        + ypart[2][rl][cc] + ypart[3][rl][cc];
                int g = clampi(batch[node], N_GRAPHS);
                if (use_lds) atomicAdd(&gred[g - gmin][cc], s);
                else atomicAdd(&gacc[g * 2 + cc], s);
            }
        }
    }
    __syncthreads();
    if (use_lds && t < gspan * 2) {
        int gg = t >> 1, c2 = t & 1;
        float v = gred[gg][c2];
        if (v != 0.f) atomicAdd(&gacc[(gmin + gg) * 2 + c2], v);
    }
}

// K7: finalize (counts from boundary diffs)
__global__ void k_fin(const float* __restrict__ gacc, const int* __restrict__ bnd,
                      const float* __restrict__ bc, float* __restrict__ out) {
    int t = blockIdx.x * blockDim.x + threadIdx.x;
    if (t < N_GRAPHS * 2) {
        int g = t >> 1, c = t & 1;
        int cnt = bnd[g + 1] - bnd[g];
        out[t] = gacc[t] / (float)(cnt > 1 ? cnt : 1) + bc[c];
    }
}

extern "C" void kernel_launch(void* const* d_in, const int* in_sizes, int n_in,
                              void* d_out, int out_size, void* d_ws, size_t ws_size,
                              hipStream_t stream) {
    const float* x  = (const float*)d_in[0];
    const int* ei   = (const int*)d_in[1];
    const int* batch= (const int*)d_in[2];
    const float* Wl = (const float*)d_in[3];
    const float* bl = (const float*)d_in[4];
    const float* Wr = (const float*)d_in[5];
    const float* Wc = (const float*)d_in[6];
    const float* bc = (const float*)d_in[7];
    float* out = (float*)d_out;

    char* ws = (char*)d_ws;
    float* gacc        = (float*)(ws + OFF_GACC);
    int* base          = (int*)(ws + OFF_BASE);
    unsigned int* sd   = (unsigned int*)(ws + OFF_SD);
    int* srcs          = (int*)(ws + OFF_SRC);
    ushort_t* xb       = (ushort_t*)(ws + OFF_SRC);  // overlays srcs after gather
    unsigned char* x8  = (unsigned char*)(ws + OFF_X8);
    int* ep            = (int*)(ws + OFF_EP);
    ushort_t* agg      = (ushort_t*)(ws + OFF_EP);   // overlays dead ep
    ushort_t* WT       = (ushort_t*)(ws + OFF_WT);
    int* bnd           = (int*)(ws + OFF_BND);
    ushort_t* lst      = (ushort_t*)(ws + OFF_LST);

    hipMemsetAsync(ws, 0, ZBYTES, stream);
    k_scatter    <<<NBLK2, 512, 0, stream>>>(ei, ep, lst);
    k_colsum     <<<NB, 128, 0, stream>>>(lst, base);
    k_scan_bucket<<<1, 512, 0, stream>>>(base);
    k_csr        <<<NB, 512, 0, stream>>>(ep, lst, base, srcs, sd);
    k_prep       <<<PREP_CONV_BLOCKS + PREP_BW_BLOCKS + PREP_BND_BLOCKS, 256, 0, stream>>>(
                     x, x8, Wl, Wr, WT, batch, bnd);
    k_gather8    <<<(N_NODES + 3) / 4, 256, 0, stream>>>(x8, sd, srcs, agg);
    k_convb      <<<(N_NODES * 16 + 255) / 256, 256, 0, stream>>>(x, xb);
    k_gemm       <<<(N_NODES + 127) / 128, 256, 0, stream>>>(agg, xb, WT, bl, Wc, batch, gacc);
    k_fin        <<<4, 256, 0, stream>>>(gacc, bnd, bc, out);
}

// Round 12
// 224.165 us; speedup vs baseline: 1.1852x; 1.0207x over previous
//
#include <hip/hip_runtime.h>

#define N_NODES 100000
#define N_EDGES 3200000
#define N_GRAPHS 512
#define IN_CH 50
#define HID 256
#define NB 391          // buckets of 256 nodes
#define NBLK2 391       // edge blocks (block-local sort)
#define EPB2 8192       // edges per block

typedef unsigned short ushort_t;
using s16x8 = __attribute__((ext_vector_type(8))) short;
using us8   = __attribute__((ext_vector_type(8))) unsigned short;
using us4   = __attribute__((ext_vector_type(4))) unsigned short;
using f32x4 = __attribute__((ext_vector_type(4))) float;
using f32x2 = __attribute__((ext_vector_type(2))) float;

__device__ __forceinline__ float bf2f(ushort_t u) {
    return __uint_as_float(((unsigned int)u) << 16);
}
__device__ __forceinline__ ushort_t f2bf(float f) {
    unsigned int x = __float_as_uint(f);
    unsigned int r = x + 0x7fffu + ((x >> 16) & 1u);
    return (ushort_t)(r >> 16);
}
__device__ __forceinline__ int clampi(int v, int hi) {
    return v < 0 ? 0 : (v >= hi ? hi - 1 : v);
}

// fp8 e4m3fn encode (RNE, saturate to 448) / decode
__device__ __forceinline__ unsigned char f2e4(float f) {
    unsigned char s = (unsigned char)((__float_as_uint(f) >> 31) << 7);
    float a = fabsf(f);
    if (a >= 0.015625f) {
        if (a > 448.f) a = 448.f;
        unsigned int u = __float_as_uint(a);
        u += 0x7FFFFu + ((u >> 20) & 1u);     // RNE into 3-bit mantissa
        int e8 = (int)(u >> 23) - 127 + 7;
        unsigned int m8 = (u >> 20) & 7u;
        if (e8 > 15) { e8 = 15; m8 = 6; }
        return s | (unsigned char)((e8 << 3) | m8);
    } else {
        int m = (int)rintf(a * 512.f);
        if (m > 7) return s | 0x08;
        return s | (unsigned char)m;
    }
}
// branchless e4m3 -> f32: exact for normals AND denormals (bit-place + 2^120 scale)
__device__ __forceinline__ float e42f(unsigned int c) {
    unsigned int w = ((c & 0x80u) << 24) | ((c & 0x7fu) << 20);
    return __uint_as_float(w) * 0x1p120f;
}

// Packed fp8 decode + packed FMA accumulate into f32x2 pairs.
#if __has_builtin(__builtin_amdgcn_cvt_pk_f32_fp8)
#define ACC4(w, m, pb)                                                     \
    do {                                                                   \
        f32x2 p01 = __builtin_amdgcn_cvt_pk_f32_fp8((int)(w), false);      \
        f32x2 p23 = __builtin_amdgcn_cvt_pk_f32_fp8((int)(w), true);       \
        a2[(pb) + 0] = p01 * (m) + a2[(pb) + 0];                           \
        a2[(pb) + 1] = p23 * (m) + a2[(pb) + 1];                           \
    } while (0)
#else
#define ACC4(w, m, pb)                                                     \
    do {                                                                   \
        f32x2 p01, p23;                                                    \
        p01[0] = e42f((w) & 0xffu);        p01[1] = e42f(((w) >> 8) & 0xffu);  \
        p23[0] = e42f(((w) >> 16) & 0xffu); p23[1] = e42f(((w) >> 24) & 0xffu); \
        a2[(pb) + 0] = p01 * (m) + a2[(pb) + 0];                           \
        a2[(pb) + 1] = p23 * (m) + a2[(pb) + 1];                           \
    } while (0)
#endif

// ---- workspace layout (bytes); proven ws_size >= 39,272,064 ----
// agg has its OWN region (no ep overlay: csrgather writes agg while ep is
// still being read by other blocks). xb overlays ep (dead after csrgather).
constexpr size_t OFF_GACC   = 0;          // 512*2*4 = 4096
constexpr size_t ZBYTES     = 8192;       // zeroed prefix
constexpr size_t OFF_AGG    = 561536;     // bf16 [N,64] = 12.8MB
constexpr size_t OFF_X8     = 13361536;   // fp8 [N,64] = 6.4MB
constexpr size_t OFF_EP     = 19761536;   // int [391][8192] = 12.8MB; xb overlays after csrgather
constexpr size_t OFF_WT     = 32573824;   // bf16 [256][128] = 65536 -> 32,639,360
constexpr size_t OFF_BND    = 32639360;   // int [N_GRAPHS+1] = 2052 -> 32,641,412
constexpr size_t OFF_LST    = 32641416;   // u16 [391][392] = 306,544 -> 32,947,960

// P1 v3: block-local counting sort (single pass, no global placement).
__global__ __launch_bounds__(512) void k_scatter(const int* __restrict__ ei,
                                                 int* __restrict__ ep,
                                                 ushort_t* __restrict__ lst) {
    __shared__ int hist[NB];
    __shared__ int sa[512];
    __shared__ int sorig[512];
    __shared__ int lstart[NB + 1];
    __shared__ int lcur[NB];
    __shared__ unsigned int eph[EPB2];

    const int blk = blockIdx.x, t = threadIdx.x;
    for (int i = t; i < NB; i += 512) hist[i] = 0;
    __syncthreads();
    const int e0 = blk * EPB2;
    int sv[16], dv[16];
#pragma unroll
    for (int j = 0; j < 16; ++j) {
        int e = e0 + j * 512 + t;
        if (e < N_EDGES) {
            sv[j] = clampi(ei[e], N_NODES);
            dv[j] = clampi(ei[N_EDGES + e], N_NODES);
        } else {
            dv[j] = -1;
        }
    }
#pragma unroll
    for (int j = 0; j < 16; ++j)
        if (dv[j] >= 0) atomicAdd(&hist[dv[j] >> 8], 1);
    __syncthreads();
    int v = (t < NB) ? hist[t] : 0;
    sa[t] = v; sorig[t] = v;
    __syncthreads();
    for (int off = 1; off < 512; off <<= 1) {
        int u = (t >= off) ? sa[t - off] : 0;
        __syncthreads();
        sa[t] += u;
        __syncthreads();
    }
    if (t < NB) { lstart[t] = sa[t] - sorig[t]; lcur[t] = sa[t] - sorig[t]; }
    if (t == NB - 1) lstart[NB] = sa[t];
    __syncthreads();
#pragma unroll
    for (int j = 0; j < 16; ++j) {
        if (dv[j] >= 0) {
            int b = dv[j] >> 8;
            int r = atomicAdd(&lcur[b], 1);
            eph[r] = ((unsigned int)sv[j] << 8) | (unsigned int)(dv[j] & 255);
        }
    }
    __syncthreads();
    int mv = lstart[NB];
    for (int i = t; i < mv; i += 512) ep[e0 + i] = (int)eph[i];
    for (int i = t; i <= NB; i += 512) lst[blk * (NB + 1) + i] = (ushort_t)lstart[i];
}

// K4 fused prep: [0,6250) conv8 (4B/thread) | buildW | bounds
#define PREP_CONV_BLOCKS 6250
#define PREP_BW_BLOCKS 128
#define PREP_BND_BLOCKS 391
__global__ __launch_bounds__(256) void k_prep(const float* __restrict__ x,
                                              unsigned char* __restrict__ x8,
                                              const float* __restrict__ Wl,
                                              const float* __restrict__ Wr,
                                              ushort_t* __restrict__ WT,
                                              const int* __restrict__ batch,
                                              int* __restrict__ bnd) {
    int blk = blockIdx.x;
    if (blk < PREP_CONV_BLOCKS) {
        int idx = blk * 256 + threadIdx.x;      // idx < N_NODES*16
        int n = idx >> 4, c4 = (idx & 15) << 2;
        uchar4 o;
        o.x = (c4 + 0 < IN_CH) ? f2e4(x[n * IN_CH + c4 + 0]) : (unsigned char)0;
        o.y = (c4 + 1 < IN_CH) ? f2e4(x[n * IN_CH + c4 + 1]) : (unsigned char)0;
        o.z = (c4 + 2 < IN_CH) ? f2e4(x[n * IN_CH + c4 + 2]) : (unsigned char)0;
        o.w = (c4 + 3 < IN_CH) ? f2e4(x[n * IN_CH + c4 + 3]) : (unsigned char)0;
        *(uchar4*)(x8 + (size_t)n * 64 + c4) = o;
    } else if (blk < PREP_CONV_BLOCKS + PREP_BW_BLOCKS) {
        int idx = (blk - PREP_CONV_BLOCKS) * 256 + threadIdx.x;
        int j = idx >> 7;
        int k = idx & 127;
        ushort_t val = 0;
        if (k < IN_CH) val = f2bf(Wl[j * IN_CH + k]);
        else if (k >= 64 && k < 64 + IN_CH) val = f2bf(Wr[j * IN_CH + (k - 64)]);
        WT[idx] = val;
    } else {
        int n = (blk - PREP_CONV_BLOCKS - PREP_BW_BLOCKS) * 256 + threadIdx.x;
        if (n >= N_NODES) return;
        int b = clampi(batch[n], N_GRAPHS);
        if (n == 0) {
            for (int g = 0; g <= b; ++g) bnd[g] = 0;
        } else {
            int a = clampi(batch[n - 1], N_GRAPHS);
            for (int g = a + 1; g <= b; ++g) bnd[g] = n;
        }
        if (n == N_NODES - 1) {
            for (int g = b + 1; g <= N_GRAPHS; ++g) bnd[g] = N_NODES;
        }
    }
}

// FUSED csr+gather: one block per bucket (256 nodes). csr-phase blocks and
// gather-phase blocks co-reside per CU -> latency phases overlap memory phases.
// srcs/sd never materialized in global: placement lands in lds_src; the edge
// payloads are cached in 20 registers between histogram and placement.
// CSR_CAP = 10240 = +22 sigma of Binomial(3.2M, 1/391); clamp is unreachable.
#define CSR_CAP 10240
__global__ __launch_bounds__(512) void k_csrgather(const int* __restrict__ ep,
                                                   const ushort_t* __restrict__ lst,
                                                   const unsigned char* __restrict__ x8,
                                                   ushort_t* __restrict__ agg) {
    __shared__ int sa[512];
    __shared__ int sorig[512];
    __shared__ int rro[NBLK2 + 1];   // exclusive offsets of runs within bucket
    __shared__ int lsa[NBLK2];       // run start within source block
    __shared__ ushort_t runof[CSR_CAP];
    __shared__ int ldeg[256];
    __shared__ int aa[256];
    __shared__ int lcur[256];
    __shared__ int excl_s[256];
    __shared__ int lds_src[CSR_CAP];

    const int b = blockIdx.x, t = threadIdx.x;

    // 1. per-run length + start (one uncoalesced round; thread t <-> block t)
    int lenv = 0;
    if (t < NBLK2) {
        int lsv = (int)lst[t * (NB + 1) + b];
        int le = (int)lst[t * (NB + 1) + b + 1];
        lenv = le - lsv;
        lsa[t] = lsv;
    }
    sa[t] = lenv; sorig[t] = lenv;
    __syncthreads();
    for (int off = 1; off < 512; off <<= 1) {
        int u = (t >= off) ? sa[t - off] : 0;
        __syncthreads();
        sa[t] += u;
        __syncthreads();
    }
    if (t < NBLK2) rro[t] = sa[t] - sorig[t];
    if (t == NBLK2 - 1) rro[NBLK2] = sa[t];
    __syncthreads();
    int m = rro[NBLK2];
    if (m > CSR_CAP) m = CSR_CAP;   // statistically unreachable

    // 2. run-id map + zero histogram
    if (t < NBLK2) {
        int o = rro[t];
        int e = o + lenv;
        if (e > CSR_CAP) e = CSR_CAP;
        for (int j = o; j < e; ++j) runof[j] = (ushort_t)t;
    }
    if (t < 256) ldeg[t] = 0;
    __syncthreads();

    // 3. flattened read (ONE latency round), payloads cached in registers
    int rv[20];
#pragma unroll
    for (int k = 0; k < 20; ++k) {
        int i = t + k * 512;
        if (i < m) {
            int r = (int)runof[i];
            rv[k] = ep[r * EPB2 + lsa[r] + (i - rro[r])];
        }
    }
    // 4. histogram from registers
#pragma unroll
    for (int k = 0; k < 20; ++k) {
        int i = t + k * 512;
        if (i < m) atomicAdd(&ldeg[rv[k] & 255], 1);
    }
    __syncthreads();
    // 5. scan ldeg (256 entries, 512 threads)
    if (t < 256) aa[t] = ldeg[t];
    __syncthreads();
    for (int off = 1; off < 256; off <<= 1) {
        int u = (t >= off && t < 256) ? aa[t - off] : 0;
        __syncthreads();
        if (t < 256) aa[t] += u;
        __syncthreads();
    }
    if (t < 256) {
        int excl = aa[t] - ldeg[t];
        excl_s[t] = excl;
        lcur[t] = excl;
    }
    __syncthreads();
    // 6. placement into LDS
#pragma unroll
    for (int k = 0; k < 20; ++k) {
        int i = t + k * 512;
        if (i < m) {
            int p = rv[k];
            int r = atomicAdd(&lcur[p & 255], 1);
            lds_src[r] = p >> 8;
        }
    }
    __syncthreads();

    // 7. gather: 8 waves, wave w handles nodes w*32 .. w*32+31
    const int wv = t >> 6;
    const int lane = t & 63;
    const int r8 = lane >> 3;
    const int c8 = lane & 7;
    const int cb = c8 << 3;
    for (int k = 0; k < 32; ++k) {
        int ln = wv * 32 + k;
        int gid = (b << 8) + ln;
        if (gid >= N_NODES) break;       // wave-uniform (depends on ln only)
        int dg = ldeg[ln];
        int st = excl_s[ln];

        f32x2 a2[4] = {};
        const int nit = (dg + 31) >> 5;
        for (int it = 0; it < nit; ++it) {
            int i0 = (it << 5) + r8;
            int i1 = i0 + 8, i2 = i0 + 16, i3 = i0 + 24;
            int s0 = lds_src[st + (i0 < dg ? i0 : 0)];
            int s1 = lds_src[st + (i1 < dg ? i1 : 0)];
            int s2 = lds_src[st + (i2 < dg ? i2 : 0)];
            int s3 = lds_src[st + (i3 < dg ? i3 : 0)];
            uint2 w0 = *(const uint2*)(x8 + (size_t)s0 * 64 + cb);
            uint2 w1 = *(const uint2*)(x8 + (size_t)s1 * 64 + cb);
            uint2 w2 = *(const uint2*)(x8 + (size_t)s2 * 64 + cb);
            uint2 w3 = *(const uint2*)(x8 + (size_t)s3 * 64 + cb);
            float m0 = i0 < dg ? 1.f : 0.f;
            float m1 = i1 < dg ? 1.f : 0.f;
            float m2 = i2 < dg ? 1.f : 0.f;
            float m3 = i3 < dg ? 1.f : 0.f;
            ACC4(w0.x, m0, 0); ACC4(w0.y, m0, 2);
            ACC4(w1.x, m1, 0); ACC4(w1.y, m1, 2);
            ACC4(w2.x, m2, 0); ACC4(w2.y, m2, 2);
            ACC4(w3.x, m3, 0); ACC4(w3.y, m3, 2);
        }
#pragma unroll
        for (int p = 0; p < 4; ++p) {
            a2[p][0] += __shfl_xor(a2[p][0], 8);
            a2[p][1] += __shfl_xor(a2[p][1], 8);
            a2[p][0] += __shfl_xor(a2[p][0], 16);
            a2[p][1] += __shfl_xor(a2[p][1], 16);
            a2[p][0] += __shfl_xor(a2[p][0], 32);
            a2[p][1] += __shfl_xor(a2[p][1], 32);
        }
        float inv = 1.0f / (float)(dg > 1 ? dg : 1);
        if (r8 == 0) {
            us8 o;
#pragma unroll
            for (int q = 0; q < 8; ++q) o[q] = f2bf(a2[q >> 1][q & 1] * inv);
            *(us8*)(agg + (size_t)gid * 64 + cb) = o;
        }
    }
}

// K4d: x fp32 [N,50] -> xb bf16 [N,64] (cols 50..63 = 0); us4-vectorized stores.
// Runs AFTER k_csrgather (xb overlays dead ep region).
__global__ __launch_bounds__(256) void k_convb(const float* __restrict__ x,
                                               ushort_t* __restrict__ xb) {
    int t = blockIdx.x * blockDim.x + threadIdx.x;
    if (t >= N_NODES * 16) return;
    int n = t >> 4, c4 = (t & 15) << 2;
    us4 o;
#pragma unroll
    for (int j = 0; j < 4; j++) {
        int c = c4 + j;
        o[j] = (c < IN_CH) ? f2bf(x[n * IN_CH + c]) : (ushort_t)0;
    }
    *(us4*)(xb + (size_t)n * 64 + c4) = o;
}

// K6 v5: fused MFMA GEMM, 128 rows/block (782 blocks, 2 rounds).
// B in registers; A staged as pure us8 copies from agg + xb (conversion-free).
__global__ __launch_bounds__(256) void k_gemm(const ushort_t* __restrict__ agg,
                                              const ushort_t* __restrict__ xb,
                                              const ushort_t* __restrict__ WT,
                                              const float* __restrict__ bl,
                                              const float* __restrict__ Wc,
                                              const int* __restrict__ batch,
                                              float* __restrict__ gacc) {
    __shared__ ushort_t Alds[64 * 136];   // row stride 136 shorts (pad 8)
    __shared__ float ypart[4][64][2];
    __shared__ float gred[64][2];

    const int t = threadIdx.x;
    const int w = t >> 6;
    const int lane = t & 63;
    const int quad = lane >> 4;
    const int r16 = lane & 15;
    const int brow0 = blockIdx.x * 128;

    if (t < 128) gred[t >> 1][t & 1] = 0.f;

    // B-fragments: wave w covers cols w*64 + 16*ni + r16; k = s*32 + quad*8 .. +7
    s16x8 bfr[4][4];
#pragma unroll
    for (int s = 0; s < 4; ++s)
#pragma unroll
        for (int ni = 0; ni < 4; ++ni)
            bfr[s][ni] = *(const s16x8*)(WT + (size_t)(w * 64 + 16 * ni + r16) * 128
                                            + s * 32 + (quad << 3));

    float blv[4], w0v[4], w1v[4];
#pragma unroll
    for (int ni = 0; ni < 4; ni++) {
        int col = w * 64 + 16 * ni + r16;
        blv[ni] = bl[col];
        w0v[ni] = Wc[col];
        w1v[ni] = Wc[HID + col];
    }

    int lastb = brow0 + 127;
    if (lastb >= N_NODES) lastb = N_NODES - 1;
    const int gmin = clampi(batch[brow0], N_GRAPHS);
    const int gmax = clampi(batch[lastb], N_GRAPHS);
    const int gspan = gmax - gmin + 1;
    const bool use_lds = (gspan <= 64);

    for (int r4 = 0; r4 < 2; ++r4) {
        const int row0 = brow0 + r4 * 64;
        __syncthreads();   // Alds/ypart safe to overwrite (covers gred init on r4==0)
        {
            int row = t >> 2;
            int q4 = t & 3;
            int gr = row0 + row;
            us8* dst = (us8*)&Alds[row * 136 + q4 * 32];
            if (gr < N_NODES) {
                const us8* src = (q4 < 2)
                    ? (const us8*)(agg + (size_t)gr * 64 + (q4 & 1) * 32)
                    : (const us8*)(xb + (size_t)gr * 64 + (q4 & 1) * 32);
                dst[0] = src[0];
                dst[1] = src[1];
                dst[2] = src[2];
                dst[3] = src[3];
            } else {
                us8 z = {0, 0, 0, 0, 0, 0, 0, 0};
                dst[0] = z; dst[1] = z; dst[2] = z; dst[3] = z;
            }
        }
        __syncthreads();

        f32x4 acc[4][4] = {};
#pragma unroll
        for (int s = 0; s < 4; ++s) {
            s16x8 af[4];
#pragma unroll
            for (int mi = 0; mi < 4; mi++)
                af[mi] = *(const s16x8*)&Alds[(16 * mi + r16) * 136 + s * 32 + (quad << 3)];
#pragma unroll
            for (int mi = 0; mi < 4; mi++)
#pragma unroll
                for (int ni = 0; ni < 4; ni++)
                    acc[mi][ni] = __builtin_amdgcn_mfma_f32_16x16x32_bf16(
                        af[mi], bfr[s][ni], acc[mi][ni], 0, 0, 0);
        }

#pragma unroll
        for (int mi = 0; mi < 4; mi++) {
#pragma unroll
            for (int r = 0; r < 4; r++) {
                float p0 = 0.f, p1 = 0.f;
#pragma unroll
                for (int ni = 0; ni < 4; ni++) {
                    float h = acc[mi][ni][r] + blv[ni];
                    h = (h > 0.f) ? h : 0.01f * h;
                    p0 = fmaf(h, w0v[ni], p0);
                    p1 = fmaf(h, w1v[ni], p1);
                }
#pragma unroll
                for (int off = 1; off < 16; off <<= 1) {
                    p0 += __shfl_xor(p0, off, 16);
                    p1 += __shfl_xor(p1, off, 16);
                }
                if (r16 == 0) {
                    int rl = 16 * mi + (quad << 2) + r;
                    ypart[w][rl][0] = p0;
                    ypart[w][rl][1] = p1;
                }
            }
        }
        __syncthreads();

        if (t < 128) {
            int rl = t >> 1, cc = t & 1;
            int node = row0 + rl;
            if (node < N_NODES) {
                float s = ypart[0][rl][cc] + ypart[1][rl][cc]
                        + ypart[2][rl][cc] + ypart[3][rl][cc];
                int g = clampi(batch[node], N_GRAPHS);
                if (use_lds) atomicAdd(&gred[g - gmin][cc], s);
                else atomicAdd(&gacc[g * 2 + cc], s);
            }
        }
    }
    __syncthreads();
    if (use_lds && t < gspan * 2) {
        int gg = t >> 1, c2 = t & 1;
        float v = gred[gg][c2];
        if (v != 0.f) atomicAdd(&gacc[(gmin + gg) * 2 + c2], v);
    }
}

// K7: finalize (counts from boundary diffs)
__global__ void k_fin(const float* __restrict__ gacc, const int* __restrict__ bnd,
                      const float* __restrict__ bc, float* __restrict__ out) {
    int t = blockIdx.x * blockDim.x + threadIdx.x;
    if (t < N_GRAPHS * 2) {
        int g = t >> 1, c = t & 1;
        int cnt = bnd[g + 1] - bnd[g];
        out[t] = gacc[t] / (float)(cnt > 1 ? cnt : 1) + bc[c];
    }
}

extern "C" void kernel_launch(void* const* d_in, const int* in_sizes, int n_in,
                              void* d_out, int out_size, void* d_ws, size_t ws_size,
                              hipStream_t stream) {
    const float* x  = (const float*)d_in[0];
    const int* ei   = (const int*)d_in[1];
    const int* batch= (const int*)d_in[2];
    const float* Wl = (const float*)d_in[3];
    const float* bl = (const float*)d_in[4];
    const float* Wr = (const float*)d_in[5];
    const float* Wc = (const float*)d_in[6];
    const float* bc = (const float*)d_in[7];
    float* out = (float*)d_out;

    char* ws = (char*)d_ws;
    float* gacc        = (float*)(ws + OFF_GACC);
    ushort_t* agg      = (ushort_t*)(ws + OFF_AGG);
    unsigned char* x8  = (unsigned char*)(ws + OFF_X8);
    int* ep            = (int*)(ws + OFF_EP);
    ushort_t* xb       = (ushort_t*)(ws + OFF_EP);   // overlays dead ep
    ushort_t* WT       = (ushort_t*)(ws + OFF_WT);
    int* bnd           = (int*)(ws + OFF_BND);
    ushort_t* lst      = (ushort_t*)(ws + OFF_LST);

    hipMemsetAsync(ws, 0, ZBYTES, stream);
    k_scatter    <<<NBLK2, 512, 0, stream>>>(ei, ep, lst);
    k_prep       <<<PREP_CONV_BLOCKS + PREP_BW_BLOCKS + PREP_BND_BLOCKS, 256, 0, stream>>>(
                     x, x8, Wl, Wr, WT, batch, bnd);
    k_csrgather  <<<NB, 512, 0, stream>>>(ep, lst, x8, agg);
    k_convb      <<<(N_NODES * 16 + 255) / 256, 256, 0, stream>>>(x, xb);
    k_gemm       <<<(N_NODES + 127) / 128, 256, 0, stream>>>(agg, xb, WT, bl, Wc, batch, gacc);
    k_fin        <<<4, 256, 0, stream>>>(gacc, bnd, bc, out);
}

// Round 13
// 209.334 us; speedup vs baseline: 1.2692x; 1.0708x over previous
//
#include <hip/hip_runtime.h>

#define N_NODES 100000
#define N_EDGES 3200000
#define N_GRAPHS 512
#define IN_CH 50
#define HID 256
#define NB 391          // buckets of 256 nodes
#define NBLK2 391       // edge blocks (block-local sort)
#define EPB2 8192       // edges per block

typedef unsigned short ushort_t;
using s16x8 = __attribute__((ext_vector_type(8))) short;
using us8   = __attribute__((ext_vector_type(8))) unsigned short;
using us4   = __attribute__((ext_vector_type(4))) unsigned short;
using f32x4 = __attribute__((ext_vector_type(4))) float;
using f32x2 = __attribute__((ext_vector_type(2))) float;

__device__ __forceinline__ float bf2f(ushort_t u) {
    return __uint_as_float(((unsigned int)u) << 16);
}
__device__ __forceinline__ ushort_t f2bf(float f) {
    unsigned int x = __float_as_uint(f);
    unsigned int r = x + 0x7fffu + ((x >> 16) & 1u);
    return (ushort_t)(r >> 16);
}
__device__ __forceinline__ int clampi(int v, int hi) {
    return v < 0 ? 0 : (v >= hi ? hi - 1 : v);
}

// fp8 e4m3fn encode (RNE, saturate to 448) / decode
__device__ __forceinline__ unsigned char f2e4(float f) {
    unsigned char s = (unsigned char)((__float_as_uint(f) >> 31) << 7);
    float a = fabsf(f);
    if (a >= 0.015625f) {
        if (a > 448.f) a = 448.f;
        unsigned int u = __float_as_uint(a);
        u += 0x7FFFFu + ((u >> 20) & 1u);     // RNE into 3-bit mantissa
        int e8 = (int)(u >> 23) - 127 + 7;
        unsigned int m8 = (u >> 20) & 7u;
        if (e8 > 15) { e8 = 15; m8 = 6; }
        return s | (unsigned char)((e8 << 3) | m8);
    } else {
        int m = (int)rintf(a * 512.f);
        if (m > 7) return s | 0x08;
        return s | (unsigned char)m;
    }
}
// branchless e4m3 -> f32: exact for normals AND denormals (bit-place + 2^120 scale)
__device__ __forceinline__ float e42f(unsigned int c) {
    unsigned int w = ((c & 0x80u) << 24) | ((c & 0x7fu) << 20);
    return __uint_as_float(w) * 0x1p120f;
}

// decode 8 fp8 bytes of a uint2, masked accumulate into 4 packed f32 pairs
__device__ __forceinline__ void acc8(f32x2 a2[4], uint2 w, float m) {
#if __has_builtin(__builtin_amdgcn_cvt_pk_f32_fp8)
    f32x2 p0 = __builtin_amdgcn_cvt_pk_f32_fp8((int)w.x, false);
    f32x2 p1 = __builtin_amdgcn_cvt_pk_f32_fp8((int)w.x, true);
    f32x2 p2 = __builtin_amdgcn_cvt_pk_f32_fp8((int)w.y, false);
    f32x2 p3 = __builtin_amdgcn_cvt_pk_f32_fp8((int)w.y, true);
#else
    f32x2 p0, p1, p2, p3;
    p0[0] = e42f(w.x & 0xffu);         p0[1] = e42f((w.x >> 8) & 0xffu);
    p1[0] = e42f((w.x >> 16) & 0xffu); p1[1] = e42f((w.x >> 24) & 0xffu);
    p2[0] = e42f(w.y & 0xffu);         p2[1] = e42f((w.y >> 8) & 0xffu);
    p3[0] = e42f((w.y >> 16) & 0xffu); p3[1] = e42f((w.y >> 24) & 0xffu);
#endif
    a2[0] = p0 * m + a2[0];
    a2[1] = p1 * m + a2[1];
    a2[2] = p2 * m + a2[2];
    a2[3] = p3 * m + a2[3];
}

__device__ __forceinline__ void wavered(f32x2 a2[4]) {
#pragma unroll
    for (int p = 0; p < 4; ++p) {
        a2[p][0] += __shfl_xor(a2[p][0], 8);
        a2[p][1] += __shfl_xor(a2[p][1], 8);
        a2[p][0] += __shfl_xor(a2[p][0], 16);
        a2[p][1] += __shfl_xor(a2[p][1], 16);
        a2[p][0] += __shfl_xor(a2[p][0], 32);
        a2[p][1] += __shfl_xor(a2[p][1], 32);
    }
}

// ---- workspace layout (bytes); proven ws_size >= 39,272,064 ----
constexpr size_t OFF_GACC   = 0;          // 512*2*4 = 4096
constexpr size_t ZBYTES     = 8192;       // zeroed prefix
constexpr size_t OFF_AGG    = 561536;     // bf16 [N,64] = 12.8MB
constexpr size_t OFF_X8     = 13361536;   // fp8 [N,64] = 6.4MB
constexpr size_t OFF_EP     = 19761536;   // int [391][8192] = 12.8MB; xb overlays after csrgather
constexpr size_t OFF_WT     = 32573824;   // bf16 [256][128] = 65536 -> 32,639,360
constexpr size_t OFF_BND    = 32639360;   // int [N_GRAPHS+1] = 2052 -> 32,641,412
constexpr size_t OFF_LST    = 32641416;   // u16 [391][392] = 306,544 -> 32,947,960

// P1 v3: block-local counting sort (single pass, no global placement).
__global__ __launch_bounds__(512) void k_scatter(const int* __restrict__ ei,
                                                 int* __restrict__ ep,
                                                 ushort_t* __restrict__ lst) {
    __shared__ int hist[NB];
    __shared__ int sa[512];
    __shared__ int sorig[512];
    __shared__ int lstart[NB + 1];
    __shared__ int lcur[NB];
    __shared__ unsigned int eph[EPB2];

    const int blk = blockIdx.x, t = threadIdx.x;
    for (int i = t; i < NB; i += 512) hist[i] = 0;
    __syncthreads();
    const int e0 = blk * EPB2;
    int sv[16], dv[16];
#pragma unroll
    for (int j = 0; j < 16; ++j) {
        int e = e0 + j * 512 + t;
        if (e < N_EDGES) {
            sv[j] = clampi(ei[e], N_NODES);
            dv[j] = clampi(ei[N_EDGES + e], N_NODES);
        } else {
            dv[j] = -1;
        }
    }
#pragma unroll
    for (int j = 0; j < 16; ++j)
        if (dv[j] >= 0) atomicAdd(&hist[dv[j] >> 8], 1);
    __syncthreads();
    int v = (t < NB) ? hist[t] : 0;
    sa[t] = v; sorig[t] = v;
    __syncthreads();
    for (int off = 1; off < 512; off <<= 1) {
        int u = (t >= off) ? sa[t - off] : 0;
        __syncthreads();
        sa[t] += u;
        __syncthreads();
    }
    if (t < NB) { lstart[t] = sa[t] - sorig[t]; lcur[t] = sa[t] - sorig[t]; }
    if (t == NB - 1) lstart[NB] = sa[t];
    __syncthreads();
#pragma unroll
    for (int j = 0; j < 16; ++j) {
        if (dv[j] >= 0) {
            int b = dv[j] >> 8;
            int r = atomicAdd(&lcur[b], 1);
            eph[r] = ((unsigned int)sv[j] << 8) | (unsigned int)(dv[j] & 255);
        }
    }
    __syncthreads();
    int mv = lstart[NB];
    for (int i = t; i < mv; i += 512) ep[e0 + i] = (int)eph[i];
    for (int i = t; i <= NB; i += 512) lst[blk * (NB + 1) + i] = (ushort_t)lstart[i];
}

// K4 fused prep: [0,6250) conv8 (4B/thread) | buildW | bounds
#define PREP_CONV_BLOCKS 6250
#define PREP_BW_BLOCKS 128
#define PREP_BND_BLOCKS 391
__global__ __launch_bounds__(256) void k_prep(const float* __restrict__ x,
                                              unsigned char* __restrict__ x8,
                                              const float* __restrict__ Wl,
                                              const float* __restrict__ Wr,
                                              ushort_t* __restrict__ WT,
                                              const int* __restrict__ batch,
                                              int* __restrict__ bnd) {
    int blk = blockIdx.x;
    if (blk < PREP_CONV_BLOCKS) {
        int idx = blk * 256 + threadIdx.x;      // idx < N_NODES*16
        int n = idx >> 4, c4 = (idx & 15) << 2;
        uchar4 o;
        o.x = (c4 + 0 < IN_CH) ? f2e4(x[n * IN_CH + c4 + 0]) : (unsigned char)0;
        o.y = (c4 + 1 < IN_CH) ? f2e4(x[n * IN_CH + c4 + 1]) : (unsigned char)0;
        o.z = (c4 + 2 < IN_CH) ? f2e4(x[n * IN_CH + c4 + 2]) : (unsigned char)0;
        o.w = (c4 + 3 < IN_CH) ? f2e4(x[n * IN_CH + c4 + 3]) : (unsigned char)0;
        *(uchar4*)(x8 + (size_t)n * 64 + c4) = o;
    } else if (blk < PREP_CONV_BLOCKS + PREP_BW_BLOCKS) {
        int idx = (blk - PREP_CONV_BLOCKS) * 256 + threadIdx.x;
        int j = idx >> 7;
        int k = idx & 127;
        ushort_t val = 0;
        if (k < IN_CH) val = f2bf(Wl[j * IN_CH + k]);
        else if (k >= 64 && k < 64 + IN_CH) val = f2bf(Wr[j * IN_CH + (k - 64)]);
        WT[idx] = val;
    } else {
        int n = (blk - PREP_CONV_BLOCKS - PREP_BW_BLOCKS) * 256 + threadIdx.x;
        if (n >= N_NODES) return;
        int b = clampi(batch[n], N_GRAPHS);
        if (n == 0) {
            for (int g = 0; g <= b; ++g) bnd[g] = 0;
        } else {
            int a = clampi(batch[n - 1], N_GRAPHS);
            for (int g = a + 1; g <= b; ++g) bnd[g] = n;
        }
        if (n == N_NODES - 1) {
            for (int g = b + 1; g <= N_GRAPHS; ++g) bnd[g] = N_NODES;
        }
    }
}

// FUSED csr+gather v2: runof unioned into lds_src (dead after phase 3; barriers
// between) and aa folded into sa -> LDS 73.2 -> ~51.3 KB. Gather phase processes
// TWO nodes per wave iteration (8 independent gathers in flight, 2x MLP).
#define CSR_CAP 10240
__global__ __launch_bounds__(512) void k_csrgather(const int* __restrict__ ep,
                                                   const ushort_t* __restrict__ lst,
                                                   const unsigned char* __restrict__ x8,
                                                   ushort_t* __restrict__ agg) {
    __shared__ int sa[512];
    __shared__ int sorig[512];
    __shared__ int rro[NBLK2 + 1];   // exclusive offsets of runs within bucket
    __shared__ int lsa[NBLK2];       // run start within source block
    __shared__ int ldeg[256];
    __shared__ int lcur[256];
    __shared__ int excl_s[256];
    __shared__ int lds_src[CSR_CAP];
    ushort_t* runof = (ushort_t*)lds_src;   // alias: runof dead before lds_src written

    const int b = blockIdx.x, t = threadIdx.x;

    // 1. per-run length + start (one uncoalesced round; thread t <-> block t)
    int lenv = 0;
    if (t < NBLK2) {
        int lsv = (int)lst[t * (NB + 1) + b];
        int le = (int)lst[t * (NB + 1) + b + 1];
        lenv = le - lsv;
        lsa[t] = lsv;
    }
    sa[t] = lenv; sorig[t] = lenv;
    __syncthreads();
    for (int off = 1; off < 512; off <<= 1) {
        int u = (t >= off) ? sa[t - off] : 0;
        __syncthreads();
        sa[t] += u;
        __syncthreads();
    }
    if (t < NBLK2) rro[t] = sa[t] - sorig[t];
    if (t == NBLK2 - 1) rro[NBLK2] = sa[t];
    __syncthreads();
    int m = rro[NBLK2];
    if (m > CSR_CAP) m = CSR_CAP;   // statistically unreachable

    // 2. run-id map (into aliased runof) + zero histogram
    if (t < NBLK2) {
        int o = rro[t];
        int e = o + lenv;
        if (e > CSR_CAP) e = CSR_CAP;
        for (int j = o; j < e; ++j) runof[j] = (ushort_t)t;
    }
    if (t < 256) ldeg[t] = 0;
    __syncthreads();

    // 3. flattened read (ONE latency round), payloads cached in registers
    int rv[20];
#pragma unroll
    for (int k = 0; k < 20; ++k) {
        int i = t + k * 512;
        if (i < m) {
            int r = (int)runof[i];
            rv[k] = ep[r * EPB2 + lsa[r] + (i - rro[r])];
        }
    }
    // 4. histogram from registers
#pragma unroll
    for (int k = 0; k < 20; ++k) {
        int i = t + k * 512;
        if (i < m) atomicAdd(&ldeg[rv[k] & 255], 1);
    }
    __syncthreads();
    // 5. scan ldeg (256 entries; sa reused)
    if (t < 256) sa[t] = ldeg[t];
    __syncthreads();
    for (int off = 1; off < 256; off <<= 1) {
        int u = (t >= off && t < 256) ? sa[t - off] : 0;
        __syncthreads();
        if (t < 256) sa[t] += u;
        __syncthreads();
    }
    if (t < 256) {
        int excl = sa[t] - ldeg[t];
        excl_s[t] = excl;
        lcur[t] = excl;
    }
    __syncthreads();
    // 6. placement into lds_src (overwrites dead runof)
#pragma unroll
    for (int k = 0; k < 20; ++k) {
        int i = t + k * 512;
        if (i < m) {
            int p = rv[k];
            int r = atomicAdd(&lcur[p & 255], 1);
            lds_src[r] = p >> 8;
        }
    }
    __syncthreads();

    // 7. gather: 8 waves x 32 nodes, TWO nodes per iteration (2x MLP)
    const int wv = t >> 6;
    const int lane = t & 63;
    const int r8 = lane >> 3;
    const int c8 = lane & 7;
    const int cb = c8 << 3;
    for (int k = 0; k < 32; k += 2) {
        int ln0 = wv * 32 + k;
        int gid0 = (b << 8) + ln0;
        if (gid0 >= N_NODES) break;       // wave-uniform
        int ok1 = (gid0 + 1 < N_NODES) ? 1 : 0;
        int dg0 = ldeg[ln0], st0 = excl_s[ln0];
        int dg1 = ok1 ? ldeg[ln0 + 1] : 0;
        int st1 = ok1 ? excl_s[ln0 + 1] : st0;

        f32x2 a2[4] = {};
        f32x2 c2[4] = {};
        int dgm = dg0 > dg1 ? dg0 : dg1;
        int nit = (dgm + 31) >> 5;
        for (int it = 0; it < nit; ++it) {
            int i0 = (it << 5) + r8;
            int i1 = i0 + 8, i2 = i0 + 16, i3 = i0 + 24;
            int sA = lds_src[st0 + (i0 < dg0 ? i0 : 0)];
            int sB = lds_src[st0 + (i1 < dg0 ? i1 : 0)];
            int sC = lds_src[st0 + (i2 < dg0 ? i2 : 0)];
            int sD = lds_src[st0 + (i3 < dg0 ? i3 : 0)];
            int sE = lds_src[st1 + (i0 < dg1 ? i0 : 0)];
            int sF = lds_src[st1 + (i1 < dg1 ? i1 : 0)];
            int sG = lds_src[st1 + (i2 < dg1 ? i2 : 0)];
            int sH = lds_src[st1 + (i3 < dg1 ? i3 : 0)];
            uint2 wA = *(const uint2*)(x8 + (size_t)sA * 64 + cb);
            uint2 wB = *(const uint2*)(x8 + (size_t)sB * 64 + cb);
            uint2 wC = *(const uint2*)(x8 + (size_t)sC * 64 + cb);
            uint2 wD = *(const uint2*)(x8 + (size_t)sD * 64 + cb);
            uint2 wE = *(const uint2*)(x8 + (size_t)sE * 64 + cb);
            uint2 wF = *(const uint2*)(x8 + (size_t)sF * 64 + cb);
            uint2 wG = *(const uint2*)(x8 + (size_t)sG * 64 + cb);
            uint2 wH = *(const uint2*)(x8 + (size_t)sH * 64 + cb);
            acc8(a2, wA, i0 < dg0 ? 1.f : 0.f);
            acc8(a2, wB, i1 < dg0 ? 1.f : 0.f);
            acc8(a2, wC, i2 < dg0 ? 1.f : 0.f);
            acc8(a2, wD, i3 < dg0 ? 1.f : 0.f);
            acc8(c2, wE, i0 < dg1 ? 1.f : 0.f);
            acc8(c2, wF, i1 < dg1 ? 1.f : 0.f);
            acc8(c2, wG, i2 < dg1 ? 1.f : 0.f);
            acc8(c2, wH, i3 < dg1 ? 1.f : 0.f);
        }
        wavered(a2);
        wavered(c2);
        if (r8 == 0) {
            float inv0 = 1.0f / (float)(dg0 > 1 ? dg0 : 1);
            us8 o;
#pragma unroll
            for (int q = 0; q < 8; ++q) o[q] = f2bf(a2[q >> 1][q & 1] * inv0);
            *(us8*)(agg + (size_t)gid0 * 64 + cb) = o;
            if (ok1) {
                float inv1 = 1.0f / (float)(dg1 > 1 ? dg1 : 1);
                us8 o1;
#pragma unroll
                for (int q = 0; q < 8; ++q) o1[q] = f2bf(c2[q >> 1][q & 1] * inv1);
                *(us8*)(agg + (size_t)(gid0 + 1) * 64 + cb) = o1;
            }
        }
    }
}

// K4d: x fp32 [N,50] -> xb bf16 [N,64] (cols 50..63 = 0); us4-vectorized stores.
// Runs AFTER k_csrgather (xb overlays dead ep region).
__global__ __launch_bounds__(256) void k_convb(const float* __restrict__ x,
                                               ushort_t* __restrict__ xb) {
    int t = blockIdx.x * blockDim.x + threadIdx.x;
    if (t >= N_NODES * 16) return;
    int n = t >> 4, c4 = (t & 15) << 2;
    us4 o;
#pragma unroll
    for (int j = 0; j < 4; j++) {
        int c = c4 + j;
        o[j] = (c < IN_CH) ? f2bf(x[n * IN_CH + c]) : (ushort_t)0;
    }
    *(us4*)(xb + (size_t)n * 64 + c4) = o;
}

// K6 v6: fused MFMA GEMM, 128 rows/block; B in registers.
// Epilogue: shuffle-reduce replaced by LDS-transpose reduction
// (yp[4][64][17] f32x2, pad 17 -> 2-way bank aliasing = free).
__global__ __launch_bounds__(256) void k_gemm(const ushort_t* __restrict__ agg,
                                              const ushort_t* __restrict__ xb,
                                              const ushort_t* __restrict__ WT,
                                              const float* __restrict__ bl,
                                              const float* __restrict__ Wc,
                                              const int* __restrict__ batch,
                                              float* __restrict__ gacc) {
    __shared__ ushort_t Alds[64 * 136];   // row stride 136 shorts (pad 8)
    __shared__ f32x2 yp[4][64][17];       // [wave][row][r16(+pad)] partial (p0,p1)
    __shared__ float gred[64][2];

    const int t = threadIdx.x;
    const int w = t >> 6;
    const int lane = t & 63;
    const int quad = lane >> 4;
    const int r16 = lane & 15;
    const int brow0 = blockIdx.x * 128;

    if (t < 128) gred[t >> 1][t & 1] = 0.f;

    // B-fragments: wave w covers cols w*64 + 16*ni + r16; k = s*32 + quad*8 .. +7
    s16x8 bfr[4][4];
#pragma unroll
    for (int s = 0; s < 4; ++s)
#pragma unroll
        for (int ni = 0; ni < 4; ++ni)
            bfr[s][ni] = *(const s16x8*)(WT + (size_t)(w * 64 + 16 * ni + r16) * 128
                                            + s * 32 + (quad << 3));

    float blv[4], w0v[4], w1v[4];
#pragma unroll
    for (int ni = 0; ni < 4; ni++) {
        int col = w * 64 + 16 * ni + r16;
        blv[ni] = bl[col];
        w0v[ni] = Wc[col];
        w1v[ni] = Wc[HID + col];
    }

    int lastb = brow0 + 127;
    if (lastb >= N_NODES) lastb = N_NODES - 1;
    const int gmin = clampi(batch[brow0], N_GRAPHS);
    const int gmax = clampi(batch[lastb], N_GRAPHS);
    const int gspan = gmax - gmin + 1;
    const bool use_lds = (gspan <= 64);

    for (int r4 = 0; r4 < 2; ++r4) {
        const int row0 = brow0 + r4 * 64;
        __syncthreads();   // Alds/yp safe to overwrite (covers gred init on r4==0)
        {
            int row = t >> 2;
            int q4 = t & 3;
            int gr = row0 + row;
            us8* dst = (us8*)&Alds[row * 136 + q4 * 32];
            if (gr < N_NODES) {
                const us8* src = (q4 < 2)
                    ? (const us8*)(agg + (size_t)gr * 64 + (q4 & 1) * 32)
                    : (const us8*)(xb + (size_t)gr * 64 + (q4 & 1) * 32);
                dst[0] = src[0];
                dst[1] = src[1];
                dst[2] = src[2];
                dst[3] = src[3];
            } else {
                us8 z = {0, 0, 0, 0, 0, 0, 0, 0};
                dst[0] = z; dst[1] = z; dst[2] = z; dst[3] = z;
            }
        }
        __syncthreads();

        f32x4 acc[4][4] = {};
#pragma unroll
        for (int s = 0; s < 4; ++s) {
            s16x8 af[4];
#pragma unroll
            for (int mi = 0; mi < 4; mi++)
                af[mi] = *(const s16x8*)&Alds[(16 * mi + r16) * 136 + s * 32 + (quad << 3)];
#pragma unroll
            for (int mi = 0; mi < 4; mi++)
#pragma unroll
                for (int ni = 0; ni < 4; ni++)
                    acc[mi][ni] = __builtin_amdgcn_mfma_f32_16x16x32_bf16(
                        af[mi], bfr[s][ni], acc[mi][ni], 0, 0, 0);
        }

        // bias + leaky + Wc partials (per-thread, over its 4 cols), to LDS
#pragma unroll
        for (int mi = 0; mi < 4; mi++) {
#pragma unroll
            for (int r = 0; r < 4; r++) {
                float p0 = 0.f, p1 = 0.f;
#pragma unroll
                for (int ni = 0; ni < 4; ni++) {
                    float h = acc[mi][ni][r] + blv[ni];
                    h = (h > 0.f) ? h : 0.01f * h;
                    p0 = fmaf(h, w0v[ni], p0);
                    p1 = fmaf(h, w1v[ni], p1);
                }
                int rl = 16 * mi + (quad << 2) + r;
                f32x2 pv; pv[0] = p0; pv[1] = p1;
                yp[w][rl][r16] = pv;
            }
        }
        __syncthreads();

        // reduce over (wave, r16): 64 threads x 64 f32x2 reads
        if (t < 64) {
            f32x2 s; s[0] = 0.f; s[1] = 0.f;
#pragma unroll
            for (int ww = 0; ww < 4; ++ww)
#pragma unroll
                for (int j = 0; j < 16; ++j)
                    s = s + yp[ww][t][j];
            int node = row0 + t;
            if (node < N_NODES) {
                int g = clampi(batch[node], N_GRAPHS);
                if (use_lds) {
                    atomicAdd(&gred[g - gmin][0], s[0]);
                    atomicAdd(&gred[g - gmin][1], s[1]);
                } else {
                    atomicAdd(&gacc[g * 2 + 0], s[0]);
                    atomicAdd(&gacc[g * 2 + 1], s[1]);
                }
            }
        }
    }
    __syncthreads();
    if (use_lds && t < gspan * 2) {
        int gg = t >> 1, c2 = t & 1;
        float v = gred[gg][c2];
        if (v != 0.f) atomicAdd(&gacc[(gmin + gg) * 2 + c2], v);
    }
}

// K7: finalize (counts from boundary diffs)
__global__ void k_fin(const float* __restrict__ gacc, const int* __restrict__ bnd,
                      const float* __restrict__ bc, float* __restrict__ out) {
    int t = blockIdx.x * blockDim.x + threadIdx.x;
    if (t < N_GRAPHS * 2) {
        int g = t >> 1, c = t & 1;
        int cnt = bnd[g + 1] - bnd[g];
        out[t] = gacc[t] / (float)(cnt > 1 ? cnt : 1) + bc[c];
    }
}

extern "C" void kernel_launch(void* const* d_in, const int* in_sizes, int n_in,
                              void* d_out, int out_size, void* d_ws, size_t ws_size,
                              hipStream_t stream) {
    const float* x  = (const float*)d_in[0];
    const int* ei   = (const int*)d_in[1];
    const int* batch= (const int*)d_in[2];
    const float* Wl = (const float*)d_in[3];
    const float* bl = (const float*)d_in[4];
    const float* Wr = (const float*)d_in[5];
    const float* Wc = (const float*)d_in[6];
    const float* bc = (const float*)d_in[7];
    float* out = (float*)d_out;

    char* ws = (char*)d_ws;
    float* gacc        = (float*)(ws + OFF_GACC);
    ushort_t* agg      = (ushort_t*)(ws + OFF_AGG);
    unsigned char* x8  = (unsigned char*)(ws + OFF_X8);
    int* ep            = (int*)(ws + OFF_EP);
    ushort_t* xb       = (ushort_t*)(ws + OFF_EP);   // overlays dead ep
    ushort_t* WT       = (ushort_t*)(ws + OFF_WT);
    int* bnd           = (int*)(ws + OFF_BND);
    ushort_t* lst      = (ushort_t*)(ws + OFF_LST);

    hipMemsetAsync(ws, 0, ZBYTES, stream);
    k_scatter    <<<NBLK2, 512, 0, stream>>>(ei, ep, lst);
    k_prep       <<<PREP_CONV_BLOCKS + PREP_BW_BLOCKS + PREP_BND_BLOCKS, 256, 0, stream>>>(
                     x, x8, Wl, Wr, WT, batch, bnd);
    k_csrgather  <<<NB, 512, 0, stream>>>(ep, lst, x8, agg);
    k_convb      <<<(N_NODES * 16 + 255) / 256, 256, 0, stream>>>(x, xb);
    k_gemm       <<<(N_NODES + 127) / 128, 256, 0, stream>>>(agg, xb, WT, bl, Wc, batch, gacc);
    k_fin        <<<4, 256, 0, stream>>>(gacc, bnd, bc, out);
}